// Round 3
// baseline (403.755 us; speedup 1.0000x reference)
//
#include <hip/hip_runtime.h>
#include <math.h>

#define F_IN   128
#define HIDC   32
#define NHEAD  4
#define CDIM   40
#define NEG_SLOPE 0.2f
#define BCAP   4096
#define OVCAP  16384
#define SCHUNK 4096

typedef __attribute__((ext_vector_type(8))) short bf16x8;   // 8 bf16 = 4 VGPRs
typedef __attribute__((ext_vector_type(4))) float f32x4;    // MFMA C/D

__device__ __forceinline__ float leakyf(float x) { return x > 0.f ? x : NEG_SLOPE * x; }

__device__ __forceinline__ float sel4(float4 v, int h) {
    return (h == 0) ? v.x : (h == 1) ? v.y : (h == 2) ? v.z : v.w;
}
__device__ __forceinline__ unsigned pack2_bf16(float a, float b) {
    unsigned ua = __float_as_uint(a);
    unsigned ub = __float_as_uint(b);
    ua = (ua + 0x7FFFu + ((ua >> 16) & 1u)) >> 16;
    ub = (ub + 0x7FFFu + ((ub >> 16) & 1u)) >> 16;
    return ua | (ub << 16);
}
__device__ __forceinline__ float2 unpack2_bf16(unsigned p) {
    return make_float2(__uint_as_float(p << 16), __uint_as_float(p & 0xFFFF0000u));
}

// ---- W pre-pack into MFMA B-fragment order --------------------------------
__global__ void wb_prep_kernel(const float* __restrict__ Wg, const float* __restrict__ Wc,
                               uint4* __restrict__ wbf)
{
    int b = blockIdx.x;            // nt*4 + ks, 0..39
    int lane = threadIdx.x;        // 0..63
    int nt = b >> 2, ks = b & 3;
    int c = nt * 16 + (lane & 15);
    int k0 = ks * 32 + (lane >> 4) * 8;
    unsigned u[4];
#pragma unroll
    for (int jj = 0; jj < 4; ++jj) {
        int k = k0 + 2 * jj;
        float a0 = (c < 128) ? Wg[(size_t)k * 128 + c] : Wc[(size_t)k * 32 + (c - 128)];
        float a1 = (c < 128) ? Wg[(size_t)(k + 1) * 128 + c] : Wc[(size_t)(k + 1) * 32 + (c - 128)];
        u[jj] = pack2_bf16(a0, a1);
    }
    wbf[(size_t)b * 64 + lane] = make_uint4(u[0], u[1], u[2], u[3]);
}

// ---- first-layer GEMM on MFMA + fused logits1 epilogue --------------------
// Output row layout: hb[node][80] unsigned = 64 GAT (128ch bf16) + 16 GCN (32ch bf16)
__global__ __launch_bounds__(256) void gemm1_mfma_kernel(
    const float* __restrict__ X, const uint4* __restrict__ wbf,
    const float* __restrict__ aw_s, const float* __restrict__ aw_d,
    unsigned* __restrict__ hb,
    float* __restrict__ as1, float* __restrict__ ad1, int n)
{
    __shared__ float Ct[64][164];
    __shared__ float sw[128], dw[128];
    const int tid = threadIdx.x;
    const int w = tid >> 6, lane = tid & 63;
    const int m = lane & 15, q = lane >> 4;
    const int node0 = blockIdx.x * 64;
    if (tid < 128) { sw[tid] = aw_s[tid]; dw[tid] = aw_d[tid]; }

    f32x4 acc[10];
#pragma unroll
    for (int t = 0; t < 10; ++t) acc[t] = (f32x4){0.f, 0.f, 0.f, 0.f};

    const int row = node0 + w * 16 + m;
    const bool rv = row < n;
#pragma unroll
    for (int ks = 0; ks < 4; ++ks) {
        uint4 pa = make_uint4(0u, 0u, 0u, 0u);
        if (rv) {
            const float* xr = X + (size_t)row * 128 + ks * 32 + q * 8;
            float4 a0 = *(const float4*)xr;
            float4 a1 = *(const float4*)(xr + 4);
            pa = make_uint4(pack2_bf16(a0.x, a0.y), pack2_bf16(a0.z, a0.w),
                            pack2_bf16(a1.x, a1.y), pack2_bf16(a1.z, a1.w));
        }
        bf16x8 af = *(bf16x8*)&pa;
#pragma unroll
        for (int nt = 0; nt < 10; ++nt) {
            uint4 pb = wbf[(size_t)(nt * 4 + ks) * 64 + lane];
            bf16x8 bfv = *(bf16x8*)&pb;
            acc[nt] = __builtin_amdgcn_mfma_f32_16x16x32_bf16(af, bfv, acc[nt], 0, 0, 0);
        }
    }
#pragma unroll
    for (int nt = 0; nt < 10; ++nt)
#pragma unroll
        for (int r = 0; r < 4; ++r)
            Ct[w * 16 + q * 4 + r][nt * 16 + m] = acc[nt][r];
    __syncthreads();

    for (int i = tid; i < 64 * 64; i += 256) {
        int nd = i >> 6, u = i & 63;
        int gn = node0 + nd;
        if (gn < n)
            hb[(size_t)gn * 80 + u] = pack2_bf16(Ct[nd][2 * u], Ct[nd][2 * u + 1]);
    }
    for (int i = tid; i < 64 * 16; i += 256) {
        int nd = i >> 4, u = i & 15;
        int gn = node0 + nd;
        if (gn < n)
            hb[(size_t)gn * 80 + 64 + u] = pack2_bf16(Ct[nd][128 + 2 * u], Ct[nd][128 + 2 * u + 1]);
    }
    {
        int nd = tid >> 2, h = tid & 3;
        int gn = node0 + nd;
        if (gn < n) {
            float s = 0.f, d = 0.f;
#pragma unroll
            for (int k = 0; k < HIDC; ++k) {
                float v = Ct[nd][h * HIDC + k];
                s = fmaf(v, sw[h * HIDC + k], s);
                d = fmaf(v, dw[h * HIDC + k], d);
            }
            as1[(size_t)gn * 4 + h] = s;
            ad1[(size_t)gn * 4 + h] = d;
        }
    }
}

// bf16-in (packed), bf16-out variant (gcn L2 gemm)
template<int K, int OUTC, int BN, int BK, int OSTRIDE_U, int OFF_U>
__global__ __launch_bounds__((OUTC / 4) * (BN / 4)) void gemm_tile_bb(
    const unsigned* __restrict__ Xb, const float* __restrict__ W,
    unsigned* __restrict__ Yb, int n)
{
    constexpr int CG = OUTC / 4;
    constexpr int NG = BN / 4;
    constexpr int NT = CG * NG;
    __shared__ float Xs[BK][BN + 4];
    __shared__ float Ws[BK][OUTC];
    const int tid = threadIdx.x;
    const int cg = tid % CG, ng = tid / CG;
    const int node0 = blockIdx.x * BN;
    float acc[4][4] = {};

    for (int kb = 0; kb < K; kb += BK) {
        for (int idx = tid; idx < BN * (BK / 8); idx += NT) {
            int nd = idx / (BK / 8);
            int kq = idx % (BK / 8);
            int gnode = node0 + nd;
            uint4 v = (gnode < n) ? *(const uint4*)&Xb[(size_t)gnode * (K / 2) + kb / 2 + kq * 4]
                                  : make_uint4(0u, 0u, 0u, 0u);
            float2 a = unpack2_bf16(v.x), b = unpack2_bf16(v.y);
            float2 c = unpack2_bf16(v.z), d = unpack2_bf16(v.w);
            Xs[kq * 8 + 0][nd] = a.x; Xs[kq * 8 + 1][nd] = a.y;
            Xs[kq * 8 + 2][nd] = b.x; Xs[kq * 8 + 3][nd] = b.y;
            Xs[kq * 8 + 4][nd] = c.x; Xs[kq * 8 + 5][nd] = c.y;
            Xs[kq * 8 + 6][nd] = d.x; Xs[kq * 8 + 7][nd] = d.y;
        }
        for (int idx = tid; idx < BK * CG; idx += NT) {
            int kk = idx / CG;
            int cq = idx % CG;
            *(float4*)&Ws[kk][cq * 4] = *(const float4*)&W[(size_t)(kb + kk) * OUTC + cq * 4];
        }
        __syncthreads();
#pragma unroll
        for (int k = 0; k < BK; ++k) {
            float4 xv = *(const float4*)&Xs[k][ng * 4];
            float4 wv = *(const float4*)&Ws[k][cg * 4];
            float xa[4] = {xv.x, xv.y, xv.z, xv.w};
            float wa[4] = {wv.x, wv.y, wv.z, wv.w};
#pragma unroll
            for (int j = 0; j < 4; ++j)
#pragma unroll
                for (int c = 0; c < 4; ++c)
                    acc[j][c] = fmaf(xa[j], wa[c], acc[j][c]);
        }
        __syncthreads();
    }

#pragma unroll
    for (int j = 0; j < 4; ++j) {
        int gnode = node0 + ng * 4 + j;
        if (gnode < n) {
            uint2 pb = make_uint2(pack2_bf16(acc[j][0], acc[j][1]),
                                  pack2_bf16(acc[j][2], acc[j][3]));
            *(uint2*)&Yb[(size_t)gnode * OSTRIDE_U + OFF_U + cg * 2] = pb;
        }
    }
}

// ---- GAT L2 GEMM (bf16 in/out) + fused logits2 epilogue --------------------
__global__ __launch_bounds__(320) void gemm2_gat_kernel(
    const unsigned* __restrict__ Xb, const float* __restrict__ W,
    const float* __restrict__ aw_s, const float* __restrict__ aw_d,
    unsigned* __restrict__ Yb, float* __restrict__ as2, float* __restrict__ ad2, int n)
{
    constexpr int K = 128, OUTC = 40, BN = 128, BK = 32;
    constexpr int CG = OUTC / 4, NT = 320;
    __shared__ float smem[32 * 132 + 32 * 40];     // 5504 floats
    float* Xs = smem;                               // [32][132]
    float* Ws = smem + 32 * 132;                    // [32][40]
    const int tid = threadIdx.x;
    const int cg = tid % CG, ng = tid / CG;
    const int node0 = blockIdx.x * BN;
    float acc[4][4] = {};

    for (int kb = 0; kb < K; kb += BK) {
        for (int idx = tid; idx < BN * (BK / 8); idx += NT) {
            int nd = idx / (BK / 8);
            int kq = idx % (BK / 8);
            int gnode = node0 + nd;
            uint4 v = (gnode < n) ? *(const uint4*)&Xb[(size_t)gnode * (K / 2) + kb / 2 + kq * 4]
                                  : make_uint4(0u, 0u, 0u, 0u);
            float2 a = unpack2_bf16(v.x), b = unpack2_bf16(v.y);
            float2 c = unpack2_bf16(v.z), d = unpack2_bf16(v.w);
            Xs[(kq * 8 + 0) * 132 + nd] = a.x; Xs[(kq * 8 + 1) * 132 + nd] = a.y;
            Xs[(kq * 8 + 2) * 132 + nd] = b.x; Xs[(kq * 8 + 3) * 132 + nd] = b.y;
            Xs[(kq * 8 + 4) * 132 + nd] = c.x; Xs[(kq * 8 + 5) * 132 + nd] = c.y;
            Xs[(kq * 8 + 6) * 132 + nd] = d.x; Xs[(kq * 8 + 7) * 132 + nd] = d.y;
        }
        for (int idx = tid; idx < BK * CG; idx += NT) {
            int kk = idx / CG;
            int cq = idx % CG;
            *(float4*)&Ws[kk * 40 + cq * 4] = *(const float4*)&W[(size_t)(kb + kk) * OUTC + cq * 4];
        }
        __syncthreads();
#pragma unroll
        for (int k = 0; k < BK; ++k) {
            float4 xv = *(const float4*)&Xs[k * 132 + ng * 4];
            float4 wv = *(const float4*)&Ws[k * 40 + cg * 4];
            float xa[4] = {xv.x, xv.y, xv.z, xv.w};
            float wa[4] = {wv.x, wv.y, wv.z, wv.w};
#pragma unroll
            for (int j = 0; j < 4; ++j)
#pragma unroll
                for (int c = 0; c < 4; ++c)
                    acc[j][c] = fmaf(xa[j], wa[c], acc[j][c]);
        }
        __syncthreads();
    }

    // global bf16 write + stage Ct for logits
    float* Ct  = smem;              // [128][41]
    float* sww = smem + 128 * 41;   // [40]
    float* dww = sww + 40;          // [40]
#pragma unroll
    for (int j = 0; j < 4; ++j) {
        int gnode = node0 + ng * 4 + j;
        if (gnode < n) {
            uint2 pb = make_uint2(pack2_bf16(acc[j][0], acc[j][1]),
                                  pack2_bf16(acc[j][2], acc[j][3]));
            *(uint2*)&Yb[(size_t)gnode * 40 + cg * 2] = pb;
        }
#pragma unroll
        for (int c = 0; c < 4; ++c)
            Ct[(ng * 4 + j) * 41 + cg * 4 + c] = acc[j][c];
    }
    if (tid < 40) { sww[tid] = aw_s[tid]; dww[tid] = aw_d[tid]; }
    __syncthreads();
    if (tid < 128) {
        int gnode = node0 + tid;
        if (gnode < n) {
            float s = 0.f, d = 0.f;
#pragma unroll
            for (int c = 0; c < 40; ++c) {
                float v = Ct[tid * 41 + c];
                s = fmaf(v, sww[c], s);
                d = fmaf(v, dww[c], d);
            }
            as2[gnode] = s;
            ad2[gnode] = d;
        }
    }
}

// ---------------- CSR build: bucketed counting sort by dst ------------------
__global__ __launch_bounds__(256) void bucket_scatter_kernel(
    const int* __restrict__ src, const int* __restrict__ dst,
    unsigned* __restrict__ bcnt, unsigned* __restrict__ bpair,
    unsigned* __restrict__ ovf_cnt, uint2* __restrict__ ovf, int e, int nbuck)
{
    __shared__ unsigned hist[512];
    __shared__ unsigned base[512];
    const int t = threadIdx.x;
    const int lo = blockIdx.x * SCHUNK;
    const int hi = min(lo + SCHUNK, e);
    for (int i = t; i < nbuck; i += 256) hist[i] = 0;
    __syncthreads();
    for (int i = lo + t; i < hi; i += 256)
        atomicAdd(&hist[((unsigned)dst[i]) >> 7], 1u);
    __syncthreads();
    for (int i = t; i < nbuck; i += 256) {
        unsigned c = hist[i];
        base[i] = c ? atomicAdd(&bcnt[i], c) : 0u;
        hist[i] = 0;
    }
    __syncthreads();
    for (int i = lo + t; i < hi; i += 256) {
        unsigned s = (unsigned)src[i], d = (unsigned)dst[i];
        unsigned b = d >> 7;
        unsigned pos = base[b] + atomicAdd(&hist[b], 1u);
        if (pos < BCAP) bpair[(size_t)b * BCAP + pos] = s | ((d & 127u) << 16);
        else {
            unsigned o = atomicAdd(ovf_cnt, 1u);
            if (o < OVCAP) ovf[o] = make_uint2(s, d);
        }
    }
}

__global__ __launch_bounds__(256) void bucket_count_kernel(
    const unsigned* __restrict__ bcnt, const unsigned* __restrict__ bpair,
    const unsigned* __restrict__ ovf_cnt, const uint2* __restrict__ ovf,
    unsigned* __restrict__ counts, int n)
{
    __shared__ unsigned lc[128];
    const int b = blockIdx.x, base = b << 7;
    if (threadIdx.x < 128) lc[threadIdx.x] = 0;
    __syncthreads();
    unsigned bc = bcnt[b];
    int cnt = (int)(bc < BCAP ? bc : BCAP);
    for (int k = threadIdx.x; k < cnt; k += 256)
        atomicAdd(&lc[bpair[(size_t)b * BCAP + k] >> 16], 1u);
    unsigned oc_u = *ovf_cnt;
    int oc = (int)(oc_u < OVCAP ? oc_u : OVCAP);
    for (int k = threadIdx.x; k < oc; k += 256) {
        uint2 pp = ovf[k];
        if ((int)(pp.y >> 7) == b) atomicAdd(&lc[pp.y & 127u], 1u);
    }
    __syncthreads();
    int i = base + threadIdx.x;
    if (threadIdx.x < 128 && i < n) counts[i] = lc[threadIdx.x];
}

__global__ __launch_bounds__(256) void scan_reduce_kernel(const unsigned* __restrict__ counts,
                                                          unsigned* __restrict__ partials, int n)
{
    __shared__ unsigned sm[256];
    int t = threadIdx.x;
    int i = blockIdx.x * 256 + t;
    unsigned v = (i < n) ? counts[i] : 0u;
    sm[t] = v;
    __syncthreads();
#pragma unroll
    for (int off = 128; off > 0; off >>= 1) {
        if (t < off) sm[t] += sm[t + off];
        __syncthreads();
    }
    if (t == 0) partials[blockIdx.x] = sm[0];
}

__global__ __launch_bounds__(256) void scan_partials_kernel(unsigned* __restrict__ partials,
                                                            unsigned* __restrict__ rs, int nb, int n)
{
    __shared__ unsigned sm[256];
    int t = threadIdx.x;
    unsigned v = (t < nb) ? partials[t] : 0u;
    sm[t] = v;
    __syncthreads();
#pragma unroll
    for (int off = 1; off < 256; off <<= 1) {
        unsigned u = (t >= off) ? sm[t - off] : 0u;
        __syncthreads();
        sm[t] += u;
        __syncthreads();
    }
    if (t < nb) partials[t] = sm[t] - v;
    if (t == 255) rs[n] = sm[255];
}

__global__ __launch_bounds__(256) void scan_write_kernel(const unsigned* __restrict__ counts,
                                                         const unsigned* __restrict__ partials,
                                                         unsigned* __restrict__ rs,
                                                         float* __restrict__ nrm, int n)
{
    __shared__ unsigned sm[256];
    int t = threadIdx.x;
    int i = blockIdx.x * 256 + t;
    unsigned c = (i < n) ? counts[i] : 0u;
    sm[t] = c;
    __syncthreads();
#pragma unroll
    for (int off = 1; off < 256; off <<= 1) {
        unsigned u = (t >= off) ? sm[t - off] : 0u;
        __syncthreads();
        sm[t] += u;
        __syncthreads();
    }
    if (i < n) {
        rs[i] = partials[blockIdx.x] + sm[t] - c;
        nrm[i] = rsqrtf((float)(c + 1u));
    }
}

__global__ __launch_bounds__(256) void bucket_place_kernel(
    const unsigned* __restrict__ bcnt, const unsigned* __restrict__ bpair,
    const unsigned* __restrict__ rs, unsigned* __restrict__ csr_src,
    unsigned* __restrict__ cursor, int n)
{
    __shared__ unsigned lc[128];
    __shared__ unsigned rbase[128];
    const int b = blockIdx.x, base = b << 7;
    if (threadIdx.x < 128) {
        lc[threadIdx.x] = 0;
        int i = base + threadIdx.x;
        rbase[threadIdx.x] = (i < n) ? rs[i] : 0u;
    }
    __syncthreads();
    unsigned bc = bcnt[b];
    int cnt = (int)(bc < BCAP ? bc : BCAP);
    for (int k = threadIdx.x; k < cnt; k += 256) {
        unsigned v = bpair[(size_t)b * BCAP + k];
        unsigned ld = v >> 16;
        unsigned r = atomicAdd(&lc[ld], 1u);
        csr_src[rbase[ld] + r] = v & 0xFFFFu;
    }
    __syncthreads();
    int i = base + threadIdx.x;
    if (threadIdx.x < 128 && i < n) cursor[i] = rbase[threadIdx.x] + lc[threadIdx.x];
}

__global__ void overflow_fill_kernel(const unsigned* __restrict__ ovf_cnt,
                                     const uint2* __restrict__ ovf,
                                     unsigned* __restrict__ cursor,
                                     unsigned* __restrict__ csr_src)
{
    unsigned oc_u = *ovf_cnt;
    int oc = (int)(oc_u < OVCAP ? oc_u : OVCAP);
    for (int k = threadIdx.x; k < oc; k += 256) {
        uint2 pp = ovf[k];
        unsigned pos = atomicAdd(&cursor[pp.y], 1u);
        csr_src[pos] = pp.x;
    }
}

// -------- fused layer-1 aggregation: 2 nodes per wave, single-pass ----------
// Wave handles nodes iA = blk*8 + wid*2 and iB = iA+1 with interleaved
// independent dependency chains (2x memory-level parallelism, preambles
// overlap). Lane L: edge-slot e=L>>4, chunk c=L&15 (uint4 = 8 of 128 GAT ch);
// chunks c<4 also carry the GCN row (offset +16 in the 20-uint4 hb row).
// After full butterfly fold (xor 16,32) every lane holds both nodes' sums;
// e==0 lanes store node A, e==1 lanes store node B.
__global__ __launch_bounds__(256) void agg1_fused_kernel(
    const unsigned* __restrict__ hb,
    const float* __restrict__ as1, const float* __restrict__ ad1,
    const float* __restrict__ nrm,
    const unsigned* __restrict__ rs, const unsigned* __restrict__ csr_src,
    const float* __restrict__ gat_b1, const float* __restrict__ gcn_b1,
    unsigned* __restrict__ xgb, unsigned* __restrict__ gaccb, int n)
{
    const int wid = threadIdx.x >> 6;
    const int lane = threadIdx.x & 63;
    const int iA = blockIdx.x * 8 + wid * 2;
    if (iA >= n) return;
    const int iB = iA + 1;
    const bool hasB = iB < n;
    const int iBs = hasB ? iB : iA;

    const float4* as1v = (const float4*)as1;
    const float4* ad1v = (const float4*)ad1;
    const uint4*  hv4  = (const uint4*)hb;     // row = 20 uint4 (16 GAT + 4 GCN)

    const int e = lane >> 4, c = lane & 15;
    const int h = c >> 2;
    const bool gc = c < 4;

    const unsigned begA = rs[iA];
    const int degA = (int)(rs[iA + 1] - begA);
    const unsigned begB = rs[iBs];
    const int degB = hasB ? (int)(rs[iB + 1] - begB) : 0;

    const float dvhA = sel4(ad1v[iA], h);
    const float dvhB = sel4(ad1v[iBs], h);
    const float niA = nrm[iA];
    const float niB = nrm[iBs];

    unsigned preA = (lane < degA) ? csr_src[begA + lane] : (unsigned)iA;
    unsigned preB = (lane < degB) ? csr_src[begB + lane] : (unsigned)iBs;

    const float eselfA = __expf(leakyf(sel4(as1v[iA], h) + dvhA));
    const float eselfB = __expf(leakyf(sel4(as1v[iBs], h) + dvhB));

    float accA[8], gaccA[8], accB[8], gaccB[8];
#pragma unroll
    for (int t = 0; t < 8; ++t) { accA[t] = 0.f; gaccA[t] = 0.f; accB[t] = 0.f; gaccB[t] = 0.f; }
    float sumwA = 0.f, sumwB = 0.f;

    if (e == 0) {                             // node A self (slot 0)
        uint4 hv = hv4[(size_t)iA * 20 + c];
        float2 p0 = unpack2_bf16(hv.x), p1 = unpack2_bf16(hv.y);
        float2 p2 = unpack2_bf16(hv.z), p3 = unpack2_bf16(hv.w);
        accA[0] = p0.x * eselfA; accA[1] = p0.y * eselfA;
        accA[2] = p1.x * eselfA; accA[3] = p1.y * eselfA;
        accA[4] = p2.x * eselfA; accA[5] = p2.y * eselfA;
        accA[6] = p3.x * eselfA; accA[7] = p3.y * eselfA;
        if (gc) {
            uint4 gv = hv4[(size_t)iA * 20 + 16 + c];
            float w2 = niA * niA;
            float2 q0 = unpack2_bf16(gv.x), q1 = unpack2_bf16(gv.y);
            float2 q2 = unpack2_bf16(gv.z), q3 = unpack2_bf16(gv.w);
            gaccA[0] = q0.x * w2; gaccA[1] = q0.y * w2;
            gaccA[2] = q1.x * w2; gaccA[3] = q1.y * w2;
            gaccA[4] = q2.x * w2; gaccA[5] = q2.y * w2;
            gaccA[6] = q3.x * w2; gaccA[7] = q3.y * w2;
        }
    }
    if (e == 1 && hasB) {                     // node B self (slot 1)
        uint4 hv = hv4[(size_t)iB * 20 + c];
        float2 p0 = unpack2_bf16(hv.x), p1 = unpack2_bf16(hv.y);
        float2 p2 = unpack2_bf16(hv.z), p3 = unpack2_bf16(hv.w);
        accB[0] = p0.x * eselfB; accB[1] = p0.y * eselfB;
        accB[2] = p1.x * eselfB; accB[3] = p1.y * eselfB;
        accB[4] = p2.x * eselfB; accB[5] = p2.y * eselfB;
        accB[6] = p3.x * eselfB; accB[7] = p3.y * eselfB;
        if (gc) {
            uint4 gv = hv4[(size_t)iB * 20 + 16 + c];
            float w2 = niB * niB;
            float2 q0 = unpack2_bf16(gv.x), q1 = unpack2_bf16(gv.y);
            float2 q2 = unpack2_bf16(gv.z), q3 = unpack2_bf16(gv.w);
            gaccB[0] = q0.x * w2; gaccB[1] = q0.y * w2;
            gaccB[2] = q1.x * w2; gaccB[3] = q1.y * w2;
            gaccB[4] = q2.x * w2; gaccB[5] = q2.y * w2;
            gaccB[6] = q3.x * w2; gaccB[7] = q3.y * w2;
        }
    }

    const int dA = degA < 64 ? degA : 64;
    const int dB = degB < 64 ? degB : 64;
    const int stepsA = (dA + 3) >> 2;
    const int stepsB = (dB + 3) >> 2;
    const int steps = stepsA > stepsB ? stepsA : stepsB;

    auto fetch = [&](unsigned pre, int deg, int selfi, int idx,
                     float4& a, uint4& hh, uint4& gg, float& nr) {
        unsigned s = __shfl(pre, idx, 64);
        if (idx >= deg) s = (unsigned)selfi;
        a = as1v[s];
        hh = hv4[(size_t)s * 20 + c];
        if (gc) { gg = hv4[(size_t)s * 20 + 16 + c]; nr = nrm[s]; }
    };

    float4 aA = make_float4(0.f, 0.f, 0.f, 0.f), aB = aA;
    uint4 hA = make_uint4(0u, 0u, 0u, 0u), hB = hA, gA = hA, gB = hA;
    float nrA = 0.f, nrB = 0.f;
    if (steps > 0) {
        fetch(preA, degA, iA, e, aA, hA, gA, nrA);
        fetch(preB, degB, iBs, e, aB, hB, gB, nrB);
    }
    for (int j = 0; j < steps; ++j) {
        float4 aA2 = aA, aB2 = aB;
        uint4 hA2 = hA, hB2 = hB, gA2 = gA, gB2 = gB;
        float nrA2 = nrA, nrB2 = nrB;
        if (j + 1 < steps) {
            fetch(preA, degA, iA, (j + 1) * 4 + e, aA2, hA2, gA2, nrA2);
            fetch(preB, degB, iBs, (j + 1) * 4 + e, aB2, hB2, gB2, nrB2);
        }
        {   // node A
            const bool val = (j * 4 + e) < degA;
            float w = __expf(leakyf(sel4(aA, h) + dvhA));
            w = val ? w : 0.f;
            sumwA += w;
            float2 p0 = unpack2_bf16(hA.x), p1 = unpack2_bf16(hA.y);
            float2 p2 = unpack2_bf16(hA.z), p3 = unpack2_bf16(hA.w);
            accA[0] = fmaf(p0.x, w, accA[0]); accA[1] = fmaf(p0.y, w, accA[1]);
            accA[2] = fmaf(p1.x, w, accA[2]); accA[3] = fmaf(p1.y, w, accA[3]);
            accA[4] = fmaf(p2.x, w, accA[4]); accA[5] = fmaf(p2.y, w, accA[5]);
            accA[6] = fmaf(p3.x, w, accA[6]); accA[7] = fmaf(p3.y, w, accA[7]);
            if (gc) {
                float cw = val ? nrA * niA : 0.f;
                float2 q0 = unpack2_bf16(gA.x), q1 = unpack2_bf16(gA.y);
                float2 q2 = unpack2_bf16(gA.z), q3 = unpack2_bf16(gA.w);
                gaccA[0] = fmaf(q0.x, cw, gaccA[0]); gaccA[1] = fmaf(q0.y, cw, gaccA[1]);
                gaccA[2] = fmaf(q1.x, cw, gaccA[2]); gaccA[3] = fmaf(q1.y, cw, gaccA[3]);
                gaccA[4] = fmaf(q2.x, cw, gaccA[4]); gaccA[5] = fmaf(q2.y, cw, gaccA[5]);
                gaccA[6] = fmaf(q3.x, cw, gaccA[6]); gaccA[7] = fmaf(q3.y, cw, gaccA[7]);
            }
        }
        {   // node B
            const bool val = (j * 4 + e) < degB;
            float w = __expf(leakyf(sel4(aB, h) + dvhB));
            w = val ? w : 0.f;
            sumwB += w;
            float2 p0 = unpack2_bf16(hB.x), p1 = unpack2_bf16(hB.y);
            float2 p2 = unpack2_bf16(hB.z), p3 = unpack2_bf16(hB.w);
            accB[0] = fmaf(p0.x, w, accB[0]); accB[1] = fmaf(p0.y, w, accB[1]);
            accB[2] = fmaf(p1.x, w, accB[2]); accB[3] = fmaf(p1.y, w, accB[3]);
            accB[4] = fmaf(p2.x, w, accB[4]); accB[5] = fmaf(p2.y, w, accB[5]);
            accB[6] = fmaf(p3.x, w, accB[6]); accB[7] = fmaf(p3.y, w, accB[7]);
            if (gc) {
                float cw = val ? nrB * niB : 0.f;
                float2 q0 = unpack2_bf16(gB.x), q1 = unpack2_bf16(gB.y);
                float2 q2 = unpack2_bf16(gB.z), q3 = unpack2_bf16(gB.w);
                gaccB[0] = fmaf(q0.x, cw, gaccB[0]); gaccB[1] = fmaf(q0.y, cw, gaccB[1]);
                gaccB[2] = fmaf(q1.x, cw, gaccB[2]); gaccB[3] = fmaf(q1.y, cw, gaccB[3]);
                gaccB[4] = fmaf(q2.x, cw, gaccB[4]); gaccB[5] = fmaf(q2.y, cw, gaccB[5]);
                gaccB[6] = fmaf(q3.x, cw, gaccB[6]); gaccB[7] = fmaf(q3.y, cw, gaccB[7]);
            }
        }
        aA = aA2; aB = aB2; hA = hA2; hB = hB2; gA = gA2; gB = gB2; nrA = nrA2; nrB = nrB2;
    }
    // rare tails: deg > 64
    for (int j4 = 64; j4 < degA; j4 += 4) {
        int idx = j4 + e;
        bool val = idx < degA;
        unsigned s = val ? csr_src[begA + idx] : (unsigned)iA;
        float w = val ? __expf(leakyf(sel4(as1v[s], h) + dvhA)) : 0.f;
        sumwA += w;
        uint4 hv = hv4[(size_t)s * 20 + c];
        float2 p0 = unpack2_bf16(hv.x), p1 = unpack2_bf16(hv.y);
        float2 p2 = unpack2_bf16(hv.z), p3 = unpack2_bf16(hv.w);
        accA[0] = fmaf(p0.x, w, accA[0]); accA[1] = fmaf(p0.y, w, accA[1]);
        accA[2] = fmaf(p1.x, w, accA[2]); accA[3] = fmaf(p1.y, w, accA[3]);
        accA[4] = fmaf(p2.x, w, accA[4]); accA[5] = fmaf(p2.y, w, accA[5]);
        accA[6] = fmaf(p3.x, w, accA[6]); accA[7] = fmaf(p3.y, w, accA[7]);
        if (gc) {
            float cw = val ? nrm[s] * niA : 0.f;
            uint4 gv = hv4[(size_t)s * 20 + 16 + c];
            float2 q0 = unpack2_bf16(gv.x), q1 = unpack2_bf16(gv.y);
            float2 q2 = unpack2_bf16(gv.z), q3 = unpack2_bf16(gv.w);
            gaccA[0] = fmaf(q0.x, cw, gaccA[0]); gaccA[1] = fmaf(q0.y, cw, gaccA[1]);
            gaccA[2] = fmaf(q1.x, cw, gaccA[2]); gaccA[3] = fmaf(q1.y, cw, gaccA[3]);
            gaccA[4] = fmaf(q2.x, cw, gaccA[4]); gaccA[5] = fmaf(q2.y, cw, gaccA[5]);
            gaccA[6] = fmaf(q3.x, cw, gaccA[6]); gaccA[7] = fmaf(q3.y, cw, gaccA[7]);
        }
    }
    for (int j4 = 64; j4 < degB; j4 += 4) {
        int idx = j4 + e;
        bool val = idx < degB;
        unsigned s = val ? csr_src[begB + idx] : (unsigned)iBs;
        float w = val ? __expf(leakyf(sel4(as1v[s], h) + dvhB)) : 0.f;
        sumwB += w;
        uint4 hv = hv4[(size_t)s * 20 + c];
        float2 p0 = unpack2_bf16(hv.x), p1 = unpack2_bf16(hv.y);
        float2 p2 = unpack2_bf16(hv.z), p3 = unpack2_bf16(hv.w);
        accB[0] = fmaf(p0.x, w, accB[0]); accB[1] = fmaf(p0.y, w, accB[1]);
        accB[2] = fmaf(p1.x, w, accB[2]); accB[3] = fmaf(p1.y, w, accB[3]);
        accB[4] = fmaf(p2.x, w, accB[4]); accB[5] = fmaf(p2.y, w, accB[5]);
        accB[6] = fmaf(p3.x, w, accB[6]); accB[7] = fmaf(p3.y, w, accB[7]);
        if (gc) {
            float cw = val ? nrm[s] * niB : 0.f;
            uint4 gv = hv4[(size_t)s * 20 + 16 + c];
            float2 q0 = unpack2_bf16(gv.x), q1 = unpack2_bf16(gv.y);
            float2 q2 = unpack2_bf16(gv.z), q3 = unpack2_bf16(gv.w);
            gaccB[0] = fmaf(q0.x, cw, gaccB[0]); gaccB[1] = fmaf(q0.y, cw, gaccB[1]);
            gaccB[2] = fmaf(q1.x, cw, gaccB[2]); gaccB[3] = fmaf(q1.y, cw, gaccB[3]);
            gaccB[4] = fmaf(q2.x, cw, gaccB[4]); gaccB[5] = fmaf(q2.y, cw, gaccB[5]);
            gaccB[6] = fmaf(q3.x, cw, gaccB[6]); gaccB[7] = fmaf(q3.y, cw, gaccB[7]);
        }
    }

    // full butterfly fold over e-slot bits (4,5): every lane gets both totals
#pragma unroll
    for (int t = 0; t < 8; ++t) {
        accA[t]  += __shfl_xor(accA[t], 16, 64);  accA[t]  += __shfl_xor(accA[t], 32, 64);
        accB[t]  += __shfl_xor(accB[t], 16, 64);  accB[t]  += __shfl_xor(accB[t], 32, 64);
        gaccA[t] += __shfl_xor(gaccA[t], 16, 64); gaccA[t] += __shfl_xor(gaccA[t], 32, 64);
        gaccB[t] += __shfl_xor(gaccB[t], 16, 64); gaccB[t] += __shfl_xor(gaccB[t], 32, 64);
    }
    sumwA += __shfl_xor(sumwA, 16, 64); sumwA += __shfl_xor(sumwA, 32, 64);
    sumwB += __shfl_xor(sumwB, 16, 64); sumwB += __shfl_xor(sumwB, 32, 64);
    const float sshA = sumwA + eselfA;
    const float sshB = sumwB + eselfB;

    if (e == 0) {                             // store node A
        float inv = 1.f / sshA;
        float4 b0 = *(const float4*)&gat_b1[c * 8];
        float4 b1 = *(const float4*)&gat_b1[c * 8 + 4];
        float o[8] = {accA[0] * inv + b0.x, accA[1] * inv + b0.y,
                      accA[2] * inv + b0.z, accA[3] * inv + b0.w,
                      accA[4] * inv + b1.x, accA[5] * inv + b1.y,
                      accA[6] * inv + b1.z, accA[7] * inv + b1.w};
#pragma unroll
        for (int t = 0; t < 8; ++t) o[t] = o[t] > 0.f ? o[t] : __expf(o[t]) - 1.f;
        uint4 pv = make_uint4(pack2_bf16(o[0], o[1]), pack2_bf16(o[2], o[3]),
                              pack2_bf16(o[4], o[5]), pack2_bf16(o[6], o[7]));
        ((uint4*)xgb)[(size_t)iA * 16 + c] = pv;
        if (gc) {
            float4 c0 = *(const float4*)&gcn_b1[c * 8];
            float4 c1 = *(const float4*)&gcn_b1[c * 8 + 4];
            float g[8] = {fmaxf(gaccA[0] + c0.x, 0.f), fmaxf(gaccA[1] + c0.y, 0.f),
                          fmaxf(gaccA[2] + c0.z, 0.f), fmaxf(gaccA[3] + c0.w, 0.f),
                          fmaxf(gaccA[4] + c1.x, 0.f), fmaxf(gaccA[5] + c1.y, 0.f),
                          fmaxf(gaccA[6] + c1.z, 0.f), fmaxf(gaccA[7] + c1.w, 0.f)};
            uint4 gv = make_uint4(pack2_bf16(g[0], g[1]), pack2_bf16(g[2], g[3]),
                                  pack2_bf16(g[4], g[5]), pack2_bf16(g[6], g[7]));
            ((uint4*)gaccb)[(size_t)iA * 4 + c] = gv;
        }
    }
    if (e == 1 && hasB) {                     // store node B
        float inv = 1.f / sshB;
        float4 b0 = *(const float4*)&gat_b1[c * 8];
        float4 b1 = *(const float4*)&gat_b1[c * 8 + 4];
        float o[8] = {accB[0] * inv + b0.x, accB[1] * inv + b0.y,
                      accB[2] * inv + b0.z, accB[3] * inv + b0.w,
                      accB[4] * inv + b1.x, accB[5] * inv + b1.y,
                      accB[6] * inv + b1.z, accB[7] * inv + b1.w};
#pragma unroll
        for (int t = 0; t < 8; ++t) o[t] = o[t] > 0.f ? o[t] : __expf(o[t]) - 1.f;
        uint4 pv = make_uint4(pack2_bf16(o[0], o[1]), pack2_bf16(o[2], o[3]),
                              pack2_bf16(o[4], o[5]), pack2_bf16(o[6], o[7]));
        ((uint4*)xgb)[(size_t)iB * 16 + c] = pv;
        if (gc) {
            float4 c0 = *(const float4*)&gcn_b1[c * 8];
            float4 c1 = *(const float4*)&gcn_b1[c * 8 + 4];
            float g[8] = {fmaxf(gaccB[0] + c0.x, 0.f), fmaxf(gaccB[1] + c0.y, 0.f),
                          fmaxf(gaccB[2] + c0.z, 0.f), fmaxf(gaccB[3] + c0.w, 0.f),
                          fmaxf(gaccB[4] + c1.x, 0.f), fmaxf(gaccB[5] + c1.y, 0.f),
                          fmaxf(gaccB[6] + c1.z, 0.f), fmaxf(gaccB[7] + c1.w, 0.f)};
            uint4 gv = make_uint4(pack2_bf16(g[0], g[1]), pack2_bf16(g[2], g[3]),
                                  pack2_bf16(g[4], g[5]), pack2_bf16(g[6], g[7]));
            ((uint4*)gaccb)[(size_t)iB * 4 + c] = gv;
        }
    }
}

// ------- fused layer-2 aggregation + head GEMM: 2 nodes per wave ------------
// Lane L: edge-slot e=L&3, chunk c=L>>2 (10 chunks: c<5 GAT / c>=5 GCN).
// After fold (xor 1,2) every lane holds both nodes' 80-ch cat vector pieces;
// head (80->40, lin_W LDS-resident transposed+padded) computed in-wave via
// compile-time readlane broadcasts; writes d_out directly.
__global__ __launch_bounds__(256) void agg2_fused_kernel(
    const unsigned* __restrict__ hg_b, const float* __restrict__ as2,
    const float* __restrict__ ad2, const float* __restrict__ nrm,
    const unsigned* __restrict__ rs, const unsigned* __restrict__ csr_src,
    const float* __restrict__ gat_b2, const float* __restrict__ gcn_b2,
    const float* __restrict__ wc_p, const float* __restrict__ wt_p,
    const float* __restrict__ lin_W, const float* __restrict__ lin_b,
    float* __restrict__ Y, int n)
{
    __shared__ __align__(16) float Wt[40 * 84];   // Wt[oc][k], stride 84 (bank spread)
    const int tid = threadIdx.x;
    for (int idx = tid; idx < 3200; idx += 256) { // lin_W[k][oc] -> Wt[oc][k]
        int k = idx / 40, oc = idx - k * 40;
        Wt[oc * 84 + k] = lin_W[idx];
    }
    __syncthreads();

    const int wid = tid >> 6;
    const int lane = tid & 63;
    const int iA = blockIdx.x * 8 + wid * 2;
    if (iA >= n) return;
    const int iB = iA + 1;
    const bool hasB = iB < n;
    const int iBs = hasB ? iB : iA;

    const unsigned begA = rs[iA];
    const int degA = (int)(rs[iA + 1] - begA);
    const unsigned begB = rs[iBs];
    const int degB = hasB ? (int)(rs[iB + 1] - begB) : 0;

    const int e = lane & 3, c = lane >> 2;
    const bool act = c < 10, isgat = c < 5;
    const float advA = ad2[iA], advB = ad2[iBs];
    const float niA = nrm[iA], niB = nrm[iBs];
    const uint4* hgv = (const uint4*)hg_b;    // row = 10 uint4

    unsigned preA = (lane < degA) ? csr_src[begA + lane] : (unsigned)iA;
    unsigned preB = (lane < degB) ? csr_src[begB + lane] : (unsigned)iBs;
    const float eselfA = __expf(leakyf(as2[iA] + advA));
    const float eselfB = __expf(leakyf(as2[iBs] + advB));

    float accA[8], accB[8];
#pragma unroll
    for (int t = 0; t < 8; ++t) { accA[t] = 0.f; accB[t] = 0.f; }
    float sumwA = 0.f, sumwB = 0.f;

    if (act && e == 0) {                      // node A self
        uint4 hv = hgv[(size_t)iA * 10 + c];
        float sw = isgat ? eselfA : niA * niA;
        float2 p0 = unpack2_bf16(hv.x), p1 = unpack2_bf16(hv.y);
        float2 p2 = unpack2_bf16(hv.z), p3 = unpack2_bf16(hv.w);
        accA[0] = p0.x * sw; accA[1] = p0.y * sw;
        accA[2] = p1.x * sw; accA[3] = p1.y * sw;
        accA[4] = p2.x * sw; accA[5] = p2.y * sw;
        accA[6] = p3.x * sw; accA[7] = p3.y * sw;
    }
    if (act && e == 1 && hasB) {              // node B self
        uint4 hv = hgv[(size_t)iB * 10 + c];
        float sw = isgat ? eselfB : niB * niB;
        float2 p0 = unpack2_bf16(hv.x), p1 = unpack2_bf16(hv.y);
        float2 p2 = unpack2_bf16(hv.z), p3 = unpack2_bf16(hv.w);
        accB[0] = p0.x * sw; accB[1] = p0.y * sw;
        accB[2] = p1.x * sw; accB[3] = p1.y * sw;
        accB[4] = p2.x * sw; accB[5] = p2.y * sw;
        accB[6] = p3.x * sw; accB[7] = p3.y * sw;
    }

    const int dA = degA < 64 ? degA : 64;
    const int dB = degB < 64 ? degB : 64;
    const int stepsA = (dA + 3) >> 2;
    const int stepsB = (dB + 3) >> 2;
    const int steps = stepsA > stepsB ? stepsA : stepsB;

    auto fetch = [&](unsigned pre, int deg, int selfi, int idx, float& aw, uint4& hh) {
        unsigned s = __shfl(pre, idx, 64);
        if (idx >= deg) s = (unsigned)selfi;
        if (act) { aw = isgat ? as2[s] : nrm[s]; hh = hgv[(size_t)s * 10 + c]; }
    };

    float awA = 0.f, awB = 0.f;
    uint4 hA = make_uint4(0u, 0u, 0u, 0u), hB = hA;
    if (steps > 0) {
        fetch(preA, degA, iA, e, awA, hA);
        fetch(preB, degB, iBs, e, awB, hB);
    }
    for (int j = 0; j < steps; ++j) {
        float awA2 = awA, awB2 = awB;
        uint4 hA2 = hA, hB2 = hB;
        if (j + 1 < steps) {
            fetch(preA, degA, iA, (j + 1) * 4 + e, awA2, hA2);
            fetch(preB, degB, iBs, (j + 1) * 4 + e, awB2, hB2);
        }
        {   // node A
            const bool val = (j * 4 + e) < degA;
            float w;
            if (isgat) { w = __expf(leakyf(awA + advA)); w = val ? w : 0.f; sumwA += w; }
            else       { w = val ? awA * niA : 0.f; }
            if (act) {
                float2 p0 = unpack2_bf16(hA.x), p1 = unpack2_bf16(hA.y);
                float2 p2 = unpack2_bf16(hA.z), p3 = unpack2_bf16(hA.w);
                accA[0] = fmaf(p0.x, w, accA[0]); accA[1] = fmaf(p0.y, w, accA[1]);
                accA[2] = fmaf(p1.x, w, accA[2]); accA[3] = fmaf(p1.y, w, accA[3]);
                accA[4] = fmaf(p2.x, w, accA[4]); accA[5] = fmaf(p2.y, w, accA[5]);
                accA[6] = fmaf(p3.x, w, accA[6]); accA[7] = fmaf(p3.y, w, accA[7]);
            }
        }
        {   // node B
            const bool val = (j * 4 + e) < degB;
            float w;
            if (isgat) { w = __expf(leakyf(awB + advB)); w = val ? w : 0.f; sumwB += w; }
            else       { w = val ? awB * niB : 0.f; }
            if (act) {
                float2 p0 = unpack2_bf16(hB.x), p1 = unpack2_bf16(hB.y);
                float2 p2 = unpack2_bf16(hB.z), p3 = unpack2_bf16(hB.w);
                accB[0] = fmaf(p0.x, w, accB[0]); accB[1] = fmaf(p0.y, w, accB[1]);
                accB[2] = fmaf(p1.x, w, accB[2]); accB[3] = fmaf(p1.y, w, accB[3]);
                accB[4] = fmaf(p2.x, w, accB[4]); accB[5] = fmaf(p2.y, w, accB[5]);
                accB[6] = fmaf(p3.x, w, accB[6]); accB[7] = fmaf(p3.y, w, accB[7]);
            }
        }
        awA = awA2; awB = awB2; hA = hA2; hB = hB2;
    }
    for (int j4 = 64; j4 < degA; j4 += 4) {   // rare tail A
        int idx = j4 + e;
        bool val = idx < degA;
        unsigned s = val ? csr_src[begA + idx] : (unsigned)iA;
        if (act) {
            float aw = isgat ? as2[s] : nrm[s];
            float w;
            if (isgat) { w = val ? __expf(leakyf(aw + advA)) : 0.f; sumwA += w; }
            else       { w = val ? aw * niA : 0.f; }
            uint4 hv = hgv[(size_t)s * 10 + c];
            float2 p0 = unpack2_bf16(hv.x), p1 = unpack2_bf16(hv.y);
            float2 p2 = unpack2_bf16(hv.z), p3 = unpack2_bf16(hv.w);
            accA[0] = fmaf(p0.x, w, accA[0]); accA[1] = fmaf(p0.y, w, accA[1]);
            accA[2] = fmaf(p1.x, w, accA[2]); accA[3] = fmaf(p1.y, w, accA[3]);
            accA[4] = fmaf(p2.x, w, accA[4]); accA[5] = fmaf(p2.y, w, accA[5]);
            accA[6] = fmaf(p3.x, w, accA[6]); accA[7] = fmaf(p3.y, w, accA[7]);
        }
    }
    for (int j4 = 64; j4 < degB; j4 += 4) {   // rare tail B
        int idx = j4 + e;
        bool val = idx < degB;
        unsigned s = val ? csr_src[begB + idx] : (unsigned)iBs;
        if (act) {
            float aw = isgat ? as2[s] : nrm[s];
            float w;
            if (isgat) { w = val ? __expf(leakyf(aw + advB)) : 0.f; sumwB += w; }
            else       { w = val ? aw * niB : 0.f; }
            uint4 hv = hgv[(size_t)s * 10 + c];
            float2 p0 = unpack2_bf16(hv.x), p1 = unpack2_bf16(hv.y);
            float2 p2 = unpack2_bf16(hv.z), p3 = unpack2_bf16(hv.w);
            accB[0] = fmaf(p0.x, w, accB[0]); accB[1] = fmaf(p0.y, w, accB[1]);
            accB[2] = fmaf(p1.x, w, accB[2]); accB[3] = fmaf(p1.y, w, accB[3]);
            accB[4] = fmaf(p2.x, w, accB[4]); accB[5] = fmaf(p2.y, w, accB[5]);
            accB[6] = fmaf(p3.x, w, accB[6]); accB[7] = fmaf(p3.y, w, accB[7]);
        }
    }

    // full butterfly fold over e bits (0,1): every lane gets both totals
#pragma unroll
    for (int t = 0; t < 8; ++t) {
        accA[t] += __shfl_xor(accA[t], 1, 64); accA[t] += __shfl_xor(accA[t], 2, 64);
        accB[t] += __shfl_xor(accB[t], 1, 64); accB[t] += __shfl_xor(accB[t], 2, 64);
    }
    sumwA += __shfl_xor(sumwA, 1, 64); sumwA += __shfl_xor(sumwA, 2, 64);
    sumwB += __shfl_xor(sumwB, 1, 64); sumwB += __shfl_xor(sumwB, 2, 64);

    // per-lane cat values (chunk c of the 80-wide cat vector), both nodes
    const float invA = 1.f / (sumwA + eselfA);
    const float invB = 1.f / (sumwB + eselfB);
    const float wtv = *wt_p, wcv = *wc_p;
    float cvA[8], cvB[8];
#pragma unroll
    for (int t = 0; t < 8; ++t) { cvA[t] = 0.f; cvB[t] = 0.f; }
    if (isgat) {
        float4 b0 = *(const float4*)&gat_b2[c * 8];
        float4 b1 = *(const float4*)&gat_b2[c * 8 + 4];
        float bb[8] = {b0.x, b0.y, b0.z, b0.w, b1.x, b1.y, b1.z, b1.w};
#pragma unroll
        for (int t = 0; t < 8; ++t) {
            cvA[t] = (accA[t] * invA + bb[t]) * wtv;
            cvB[t] = (accB[t] * invB + bb[t]) * wtv;
        }
    } else if (act) {
        float4 b0 = *(const float4*)&gcn_b2[(c - 5) * 8];
        float4 b1 = *(const float4*)&gcn_b2[(c - 5) * 8 + 4];
        float bb[8] = {b0.x, b0.y, b0.z, b0.w, b1.x, b1.y, b1.z, b1.w};
#pragma unroll
        for (int t = 0; t < 8; ++t) {
            cvA[t] = (accA[t] + bb[t]) * wcv;
            cvB[t] = (accB[t] + bb[t]) * wcv;
        }
    }

    // head: out[oc] = lin_b[oc] + sum_k cat[k] * lin_W[k][oc]
    // cat order: k<40 = gcn (agg chunk 5+kc), k>=40 = gat (agg chunk kc-5)
    const int oc = lane < 40 ? lane : 0;
    const float lb = lin_b[oc];
    float oA = lb, oB = lb;
#pragma unroll
    for (int kc = 0; kc < 10; ++kc) {
        const int srcl = 4 * (kc < 5 ? 5 + kc : kc - 5);
        float4 w0 = *(const float4*)&Wt[oc * 84 + kc * 8];
        float4 w1 = *(const float4*)&Wt[oc * 84 + kc * 8 + 4];
        float wv[8] = {w0.x, w0.y, w0.z, w0.w, w1.x, w1.y, w1.z, w1.w};
#pragma unroll
        for (int t = 0; t < 8; ++t) {
            float ca = __shfl(cvA[t], srcl, 64);
            float cb = __shfl(cvB[t], srcl, 64);
            oA = fmaf(ca, wv[t], oA);
            oB = fmaf(cb, wv[t], oB);
        }
    }
    if (lane < 40) {
        Y[(size_t)iA * 40 + lane] = oA;
        if (hasB) Y[(size_t)iB * 40 + lane] = oB;
    }
}

// ---------------- host ------------------------------------------------------
extern "C" void kernel_launch(void* const* d_in, const int* in_sizes, int n_in,
                              void* d_out, int out_size, void* d_ws, size_t ws_size,
                              hipStream_t stream)
{
    const float* x        = (const float*)d_in[0];
    const int*   eidx     = (const int*)d_in[1];
    const float* gat_W1   = (const float*)d_in[2];
    const float* att_s1   = (const float*)d_in[3];
    const float* att_d1   = (const float*)d_in[4];
    const float* gat_b1   = (const float*)d_in[5];
    const float* gat_W2   = (const float*)d_in[6];
    const float* att_s2   = (const float*)d_in[7];
    const float* att_d2   = (const float*)d_in[8];
    const float* gat_b2   = (const float*)d_in[9];
    const float* gcn_W1   = (const float*)d_in[10];
    const float* gcn_b1   = (const float*)d_in[11];
    const float* gcn_W2   = (const float*)d_in[12];
    const float* gcn_b2   = (const float*)d_in[13];
    const float* lin_W    = (const float*)d_in[14];
    const float* lin_b    = (const float*)d_in[15];
    const float* wc_p     = (const float*)d_in[16];
    const float* wt_p     = (const float*)d_in[17];

    const int n = in_sizes[0] / F_IN;      // 50000
    const int e = in_sizes[1] / 2;         // 800000
    const int* src = eidx;
    const int* dst = eidx + e;
    const int NBUCK = (n + 127) >> 7;      // 391

    char* p = (char*)d_ws;
    auto alloc = [&](size_t bytes) -> void* {
        void* r = (void*)p;
        p += (bytes + 255) & ~(size_t)255;
        return r;
    };
    unsigned* counts  = (unsigned*)alloc((size_t)n * 4);
    unsigned* rs      = (unsigned*)alloc((size_t)(n + 1) * 4);
    unsigned* cursor  = (unsigned*)alloc((size_t)n * 4);
    unsigned* partials= (unsigned*)alloc(256 * 4);
    unsigned* bcnt    = (unsigned*)alloc((size_t)(NBUCK + 1) * 4);
    unsigned* csr_src = (unsigned*)alloc((size_t)e * 4);
    uint4*    wbf     = (uint4*)alloc(40 * 64 * 16);
    float* nrm     = (float*)alloc((size_t)n * 4);
    float* as1     = (float*)alloc((size_t)n * 4 * 4);
    float* ad1     = (float*)alloc((size_t)n * 4 * 4);
    float* as2     = (float*)alloc((size_t)n * 4);
    float* ad2     = (float*)alloc((size_t)n * 4);
    unsigned* hb   = (unsigned*)alloc((size_t)n * 80 * 4); // h1 staging; earlier: bpair/ovf
    unsigned* hg_b = (unsigned*)alloc((size_t)n * 40 * 4);
    float* xg      = (float*)alloc((size_t)n * F_IN * 4); // xgb bf16
    unsigned* gaccb= (unsigned*)alloc((size_t)n * 16 * 4);
    // aliases with disjoint lifetimes (stream-ordered):
    unsigned* bpair = hb;
    uint2*    ovf   = (uint2*)(bpair + (size_t)NBUCK * BCAP);
    unsigned* xgb   = (unsigned*)xg;
    unsigned* ovf_cnt = bcnt + NBUCK;

    const int NB = (n + 255) / 256;
    const int WB2 = (n + 7) / 8;
    const int SB = (e + SCHUNK - 1) / SCHUNK;

    // ---- CSR build ----
    hipMemsetAsync(bcnt, 0, (size_t)(NBUCK + 1) * 4, stream);
    bucket_scatter_kernel<<<SB, 256, 0, stream>>>(src, dst, bcnt, bpair, ovf_cnt, ovf, e, NBUCK);
    bucket_count_kernel<<<NBUCK, 256, 0, stream>>>(bcnt, bpair, ovf_cnt, ovf, counts, n);
    scan_reduce_kernel<<<NB, 256, 0, stream>>>(counts, partials, n);
    scan_partials_kernel<<<1, 256, 0, stream>>>(partials, rs, NB, n);
    scan_write_kernel<<<NB, 256, 0, stream>>>(counts, partials, rs, nrm, n);
    bucket_place_kernel<<<NBUCK, 256, 0, stream>>>(bcnt, bpair, rs, csr_src, cursor, n);
    overflow_fill_kernel<<<1, 256, 0, stream>>>(ovf_cnt, ovf, cursor, csr_src);

    // ---- W pre-pack + MFMA first-layer GEMM (fused logits1) ----
    wb_prep_kernel<<<40, 64, 0, stream>>>(gat_W1, gcn_W1, wbf);
    gemm1_mfma_kernel<<<(n + 63) / 64, 256, 0, stream>>>(x, wbf, att_s1, att_d1,
                                                         hb, as1, ad1, n);

    // ---- fused layer-1 aggregation (2 nodes/wave) ----
    agg1_fused_kernel<<<WB2, 256, 0, stream>>>(hb, as1, ad1, nrm, rs, csr_src,
                                               gat_b1, gcn_b1, xgb, gaccb, n);

    // ---- layer-2 GEMMs into hg_b (gat gemm fuses logits2) ----
    gemm_tile_bb<32, 40, 128, 32, 40, 20><<<(n + 127) / 128, 320, 0, stream>>>(gaccb, gcn_W2, hg_b, n);
    gemm2_gat_kernel<<<(n + 127) / 128, 320, 0, stream>>>(xgb, gat_W2, att_s2, att_d2,
                                                          hg_b, as2, ad2, n);

    // ---- fused layer-2 aggregation + head -> d_out ----
    agg2_fused_kernel<<<WB2, 256, 0, stream>>>(hg_b, as2, ad2, nrm, rs, csr_src,
                                               gat_b2, gcn_b2, wc_p, wt_p,
                                               lin_W, lin_b, (float*)d_out, n);
}

// Round 4
// 320.932 us; speedup vs baseline: 1.2581x; 1.2581x over previous
//
#include <hip/hip_runtime.h>
#include <math.h>

#define F_IN   128
#define HIDC   32
#define NHEAD  4
#define CDIM   40
#define NEG_SLOPE 0.2f
#define BCAP   4096
#define OVCAP  16384
#define SCHUNK 4096

typedef __attribute__((ext_vector_type(8))) short bf16x8;   // 8 bf16 = 4 VGPRs
typedef __attribute__((ext_vector_type(4))) float f32x4;    // MFMA C/D

__device__ __forceinline__ float leakyf(float x) { return x > 0.f ? x : NEG_SLOPE * x; }

__device__ __forceinline__ float sel4(float4 v, int h) {
    return (h == 0) ? v.x : (h == 1) ? v.y : (h == 2) ? v.z : v.w;
}
__device__ __forceinline__ unsigned pack2_bf16(float a, float b) {
    unsigned ua = __float_as_uint(a);
    unsigned ub = __float_as_uint(b);
    ua = (ua + 0x7FFFu + ((ua >> 16) & 1u)) >> 16;
    ub = (ub + 0x7FFFu + ((ub >> 16) & 1u)) >> 16;
    return ua | (ub << 16);
}
__device__ __forceinline__ float2 unpack2_bf16(unsigned p) {
    return make_float2(__uint_as_float(p << 16), __uint_as_float(p & 0xFFFF0000u));
}

// ---- W pre-pack into MFMA B-fragment order --------------------------------
__global__ void wb_prep_kernel(const float* __restrict__ Wg, const float* __restrict__ Wc,
                               uint4* __restrict__ wbf)
{
    int b = blockIdx.x;            // nt*4 + ks, 0..39
    int lane = threadIdx.x;        // 0..63
    int nt = b >> 2, ks = b & 3;
    int c = nt * 16 + (lane & 15);
    int k0 = ks * 32 + (lane >> 4) * 8;
    unsigned u[4];
#pragma unroll
    for (int jj = 0; jj < 4; ++jj) {
        int k = k0 + 2 * jj;
        float a0 = (c < 128) ? Wg[(size_t)k * 128 + c] : Wc[(size_t)k * 32 + (c - 128)];
        float a1 = (c < 128) ? Wg[(size_t)(k + 1) * 128 + c] : Wc[(size_t)(k + 1) * 32 + (c - 128)];
        u[jj] = pack2_bf16(a0, a1);
    }
    wbf[(size_t)b * 64 + lane] = make_uint4(u[0], u[1], u[2], u[3]);
}

// ---- first-layer GEMM on MFMA + fused logits1 epilogue --------------------
// Output row layout: hb[node][80] unsigned = 64 GAT (128ch bf16) + 16 GCN (32ch bf16)
__global__ __launch_bounds__(256) void gemm1_mfma_kernel(
    const float* __restrict__ X, const uint4* __restrict__ wbf,
    const float* __restrict__ aw_s, const float* __restrict__ aw_d,
    unsigned* __restrict__ hb,
    float* __restrict__ as1, float* __restrict__ ad1, int n)
{
    __shared__ float Ct[64][164];
    __shared__ float sw[128], dw[128];
    const int tid = threadIdx.x;
    const int w = tid >> 6, lane = tid & 63;
    const int m = lane & 15, q = lane >> 4;
    const int node0 = blockIdx.x * 64;
    if (tid < 128) { sw[tid] = aw_s[tid]; dw[tid] = aw_d[tid]; }

    f32x4 acc[10];
#pragma unroll
    for (int t = 0; t < 10; ++t) acc[t] = (f32x4){0.f, 0.f, 0.f, 0.f};

    const int row = node0 + w * 16 + m;
    const bool rv = row < n;
#pragma unroll
    for (int ks = 0; ks < 4; ++ks) {
        uint4 pa = make_uint4(0u, 0u, 0u, 0u);
        if (rv) {
            const float* xr = X + (size_t)row * 128 + ks * 32 + q * 8;
            float4 a0 = *(const float4*)xr;
            float4 a1 = *(const float4*)(xr + 4);
            pa = make_uint4(pack2_bf16(a0.x, a0.y), pack2_bf16(a0.z, a0.w),
                            pack2_bf16(a1.x, a1.y), pack2_bf16(a1.z, a1.w));
        }
        bf16x8 af = *(bf16x8*)&pa;
#pragma unroll
        for (int nt = 0; nt < 10; ++nt) {
            uint4 pb = wbf[(size_t)(nt * 4 + ks) * 64 + lane];
            bf16x8 bfv = *(bf16x8*)&pb;
            acc[nt] = __builtin_amdgcn_mfma_f32_16x16x32_bf16(af, bfv, acc[nt], 0, 0, 0);
        }
    }
#pragma unroll
    for (int nt = 0; nt < 10; ++nt)
#pragma unroll
        for (int r = 0; r < 4; ++r)
            Ct[w * 16 + q * 4 + r][nt * 16 + m] = acc[nt][r];
    __syncthreads();

    for (int i = tid; i < 64 * 64; i += 256) {
        int nd = i >> 6, u = i & 63;
        int gn = node0 + nd;
        if (gn < n)
            hb[(size_t)gn * 80 + u] = pack2_bf16(Ct[nd][2 * u], Ct[nd][2 * u + 1]);
    }
    for (int i = tid; i < 64 * 16; i += 256) {
        int nd = i >> 4, u = i & 15;
        int gn = node0 + nd;
        if (gn < n)
            hb[(size_t)gn * 80 + 64 + u] = pack2_bf16(Ct[nd][128 + 2 * u], Ct[nd][128 + 2 * u + 1]);
    }
    {
        int nd = tid >> 2, h = tid & 3;
        int gn = node0 + nd;
        if (gn < n) {
            float s = 0.f, d = 0.f;
#pragma unroll
            for (int k = 0; k < HIDC; ++k) {
                float v = Ct[nd][h * HIDC + k];
                s = fmaf(v, sw[h * HIDC + k], s);
                d = fmaf(v, dw[h * HIDC + k], d);
            }
            as1[(size_t)gn * 4 + h] = s;
            ad1[(size_t)gn * 4 + h] = d;
        }
    }
}

// ---------------- tiled GEMM (fp32 in/out, head) ----------------------------
template<int K, int OUTC, int BN, int BK, int OSTRIDE = OUTC>
__global__ __launch_bounds__((OUTC / 4) * (BN / 4)) void gemm_tile(
    const float* __restrict__ X, const float* __restrict__ W,
    const float* __restrict__ bias, float* __restrict__ Y, int n)
{
    constexpr int CG = OUTC / 4;
    constexpr int NG = BN / 4;
    constexpr int NT = CG * NG;
    __shared__ float Xs[BK][BN + 4];
    __shared__ float Ws[BK][OUTC];
    const int tid = threadIdx.x;
    const int cg = tid % CG, ng = tid / CG;
    const int node0 = blockIdx.x * BN;
    float acc[4][4] = {};

    for (int kb = 0; kb < K; kb += BK) {
        for (int idx = tid; idx < BN * (BK / 4); idx += NT) {
            int nd = idx / (BK / 4);
            int kq = idx % (BK / 4);
            int gnode = node0 + nd;
            float4 v = (gnode < n) ? *(const float4*)&X[(size_t)gnode * K + kb + kq * 4]
                                   : make_float4(0.f, 0.f, 0.f, 0.f);
            Xs[kq * 4 + 0][nd] = v.x;
            Xs[kq * 4 + 1][nd] = v.y;
            Xs[kq * 4 + 2][nd] = v.z;
            Xs[kq * 4 + 3][nd] = v.w;
        }
        for (int idx = tid; idx < BK * CG; idx += NT) {
            int kk = idx / CG;
            int cq = idx % CG;
            *(float4*)&Ws[kk][cq * 4] = *(const float4*)&W[(size_t)(kb + kk) * OUTC + cq * 4];
        }
        __syncthreads();
#pragma unroll
        for (int k = 0; k < BK; ++k) {
            float4 xv = *(const float4*)&Xs[k][ng * 4];
            float4 wv = *(const float4*)&Ws[k][cg * 4];
            float xa[4] = {xv.x, xv.y, xv.z, xv.w};
            float wa[4] = {wv.x, wv.y, wv.z, wv.w};
#pragma unroll
            for (int j = 0; j < 4; ++j)
#pragma unroll
                for (int c = 0; c < 4; ++c)
                    acc[j][c] = fmaf(xa[j], wa[c], acc[j][c]);
        }
        __syncthreads();
    }

    float4 bv = make_float4(0.f, 0.f, 0.f, 0.f);
    if (bias) bv = *(const float4*)&bias[cg * 4];
#pragma unroll
    for (int j = 0; j < 4; ++j) {
        int gnode = node0 + ng * 4 + j;
        if (gnode < n) {
            float4 o = make_float4(acc[j][0] + bv.x, acc[j][1] + bv.y,
                                   acc[j][2] + bv.z, acc[j][3] + bv.w);
            *(float4*)&Y[(size_t)gnode * OSTRIDE + cg * 4] = o;
        }
    }
}

// bf16-in (packed), bf16-out variant (gcn L2 gemm)
template<int K, int OUTC, int BN, int BK, int OSTRIDE_U, int OFF_U>
__global__ __launch_bounds__((OUTC / 4) * (BN / 4)) void gemm_tile_bb(
    const unsigned* __restrict__ Xb, const float* __restrict__ W,
    unsigned* __restrict__ Yb, int n)
{
    constexpr int CG = OUTC / 4;
    constexpr int NG = BN / 4;
    constexpr int NT = CG * NG;
    __shared__ float Xs[BK][BN + 4];
    __shared__ float Ws[BK][OUTC];
    const int tid = threadIdx.x;
    const int cg = tid % CG, ng = tid / CG;
    const int node0 = blockIdx.x * BN;
    float acc[4][4] = {};

    for (int kb = 0; kb < K; kb += BK) {
        for (int idx = tid; idx < BN * (BK / 8); idx += NT) {
            int nd = idx / (BK / 8);
            int kq = idx % (BK / 8);
            int gnode = node0 + nd;
            uint4 v = (gnode < n) ? *(const uint4*)&Xb[(size_t)gnode * (K / 2) + kb / 2 + kq * 4]
                                  : make_uint4(0u, 0u, 0u, 0u);
            float2 a = unpack2_bf16(v.x), b = unpack2_bf16(v.y);
            float2 c = unpack2_bf16(v.z), d = unpack2_bf16(v.w);
            Xs[kq * 8 + 0][nd] = a.x; Xs[kq * 8 + 1][nd] = a.y;
            Xs[kq * 8 + 2][nd] = b.x; Xs[kq * 8 + 3][nd] = b.y;
            Xs[kq * 8 + 4][nd] = c.x; Xs[kq * 8 + 5][nd] = c.y;
            Xs[kq * 8 + 6][nd] = d.x; Xs[kq * 8 + 7][nd] = d.y;
        }
        for (int idx = tid; idx < BK * CG; idx += NT) {
            int kk = idx / CG;
            int cq = idx % CG;
            *(float4*)&Ws[kk][cq * 4] = *(const float4*)&W[(size_t)(kb + kk) * OUTC + cq * 4];
        }
        __syncthreads();
#pragma unroll
        for (int k = 0; k < BK; ++k) {
            float4 xv = *(const float4*)&Xs[k][ng * 4];
            float4 wv = *(const float4*)&Ws[k][cg * 4];
            float xa[4] = {xv.x, xv.y, xv.z, xv.w};
            float wa[4] = {wv.x, wv.y, wv.z, wv.w};
#pragma unroll
            for (int j = 0; j < 4; ++j)
#pragma unroll
                for (int c = 0; c < 4; ++c)
                    acc[j][c] = fmaf(xa[j], wa[c], acc[j][c]);
        }
        __syncthreads();
    }

#pragma unroll
    for (int j = 0; j < 4; ++j) {
        int gnode = node0 + ng * 4 + j;
        if (gnode < n) {
            uint2 pb = make_uint2(pack2_bf16(acc[j][0], acc[j][1]),
                                  pack2_bf16(acc[j][2], acc[j][3]));
            *(uint2*)&Yb[(size_t)gnode * OSTRIDE_U + OFF_U + cg * 2] = pb;
        }
    }
}

// ---- GAT L2 GEMM (bf16 in/out) + fused logits2 epilogue --------------------
__global__ __launch_bounds__(320) void gemm2_gat_kernel(
    const unsigned* __restrict__ Xb, const float* __restrict__ W,
    const float* __restrict__ aw_s, const float* __restrict__ aw_d,
    unsigned* __restrict__ Yb, float* __restrict__ as2, float* __restrict__ ad2, int n)
{
    constexpr int K = 128, OUTC = 40, BN = 128, BK = 32;
    constexpr int CG = OUTC / 4, NT = 320;
    __shared__ float smem[32 * 132 + 32 * 40];     // 5504 floats
    float* Xs = smem;                               // [32][132]
    float* Ws = smem + 32 * 132;                    // [32][40]
    const int tid = threadIdx.x;
    const int cg = tid % CG, ng = tid / CG;
    const int node0 = blockIdx.x * BN;
    float acc[4][4] = {};

    for (int kb = 0; kb < K; kb += BK) {
        for (int idx = tid; idx < BN * (BK / 8); idx += NT) {
            int nd = idx / (BK / 8);
            int kq = idx % (BK / 8);
            int gnode = node0 + nd;
            uint4 v = (gnode < n) ? *(const uint4*)&Xb[(size_t)gnode * (K / 2) + kb / 2 + kq * 4]
                                  : make_uint4(0u, 0u, 0u, 0u);
            float2 a = unpack2_bf16(v.x), b = unpack2_bf16(v.y);
            float2 c = unpack2_bf16(v.z), d = unpack2_bf16(v.w);
            Xs[(kq * 8 + 0) * 132 + nd] = a.x; Xs[(kq * 8 + 1) * 132 + nd] = a.y;
            Xs[(kq * 8 + 2) * 132 + nd] = b.x; Xs[(kq * 8 + 3) * 132 + nd] = b.y;
            Xs[(kq * 8 + 4) * 132 + nd] = c.x; Xs[(kq * 8 + 5) * 132 + nd] = c.y;
            Xs[(kq * 8 + 6) * 132 + nd] = d.x; Xs[(kq * 8 + 7) * 132 + nd] = d.y;
        }
        for (int idx = tid; idx < BK * CG; idx += NT) {
            int kk = idx / CG;
            int cq = idx % CG;
            *(float4*)&Ws[kk * 40 + cq * 4] = *(const float4*)&W[(size_t)(kb + kk) * OUTC + cq * 4];
        }
        __syncthreads();
#pragma unroll
        for (int k = 0; k < BK; ++k) {
            float4 xv = *(const float4*)&Xs[k * 132 + ng * 4];
            float4 wv = *(const float4*)&Ws[k * 40 + cg * 4];
            float xa[4] = {xv.x, xv.y, xv.z, xv.w};
            float wa[4] = {wv.x, wv.y, wv.z, wv.w};
#pragma unroll
            for (int j = 0; j < 4; ++j)
#pragma unroll
                for (int c = 0; c < 4; ++c)
                    acc[j][c] = fmaf(xa[j], wa[c], acc[j][c]);
        }
        __syncthreads();
    }

    // global bf16 write + stage Ct for logits
    float* Ct  = smem;              // [128][41]
    float* sww = smem + 128 * 41;   // [40]
    float* dww = sww + 40;          // [40]
#pragma unroll
    for (int j = 0; j < 4; ++j) {
        int gnode = node0 + ng * 4 + j;
        if (gnode < n) {
            uint2 pb = make_uint2(pack2_bf16(acc[j][0], acc[j][1]),
                                  pack2_bf16(acc[j][2], acc[j][3]));
            *(uint2*)&Yb[(size_t)gnode * 40 + cg * 2] = pb;
        }
#pragma unroll
        for (int c = 0; c < 4; ++c)
            Ct[(ng * 4 + j) * 41 + cg * 4 + c] = acc[j][c];
    }
    if (tid < 40) { sww[tid] = aw_s[tid]; dww[tid] = aw_d[tid]; }
    __syncthreads();
    if (tid < 128) {
        int gnode = node0 + tid;
        if (gnode < n) {
            float s = 0.f, d = 0.f;
#pragma unroll
            for (int c = 0; c < 40; ++c) {
                float v = Ct[tid * 41 + c];
                s = fmaf(v, sww[c], s);
                d = fmaf(v, dww[c], d);
            }
            as2[gnode] = s;
            ad2[gnode] = d;
        }
    }
}

// ---------------- CSR build: bucketed counting sort by dst ------------------
__global__ __launch_bounds__(256) void bucket_scatter_kernel(
    const int* __restrict__ src, const int* __restrict__ dst,
    unsigned* __restrict__ bcnt, unsigned* __restrict__ bpair,
    unsigned* __restrict__ ovf_cnt, uint2* __restrict__ ovf, int e, int nbuck)
{
    __shared__ unsigned hist[512];
    __shared__ unsigned base[512];
    const int t = threadIdx.x;
    const int lo = blockIdx.x * SCHUNK;
    const int hi = min(lo + SCHUNK, e);
    for (int i = t; i < nbuck; i += 256) hist[i] = 0;
    __syncthreads();
    for (int i = lo + t; i < hi; i += 256)
        atomicAdd(&hist[((unsigned)dst[i]) >> 7], 1u);
    __syncthreads();
    for (int i = t; i < nbuck; i += 256) {
        unsigned c = hist[i];
        base[i] = c ? atomicAdd(&bcnt[i], c) : 0u;
        hist[i] = 0;
    }
    __syncthreads();
    for (int i = lo + t; i < hi; i += 256) {
        unsigned s = (unsigned)src[i], d = (unsigned)dst[i];
        unsigned b = d >> 7;
        unsigned pos = base[b] + atomicAdd(&hist[b], 1u);
        if (pos < BCAP) bpair[(size_t)b * BCAP + pos] = s | ((d & 127u) << 16);
        else {
            unsigned o = atomicAdd(ovf_cnt, 1u);
            if (o < OVCAP) ovf[o] = make_uint2(s, d);
        }
    }
}

__global__ __launch_bounds__(256) void bucket_count_kernel(
    const unsigned* __restrict__ bcnt, const unsigned* __restrict__ bpair,
    const unsigned* __restrict__ ovf_cnt, const uint2* __restrict__ ovf,
    unsigned* __restrict__ counts, int n)
{
    __shared__ unsigned lc[128];
    const int b = blockIdx.x, base = b << 7;
    if (threadIdx.x < 128) lc[threadIdx.x] = 0;
    __syncthreads();
    unsigned bc = bcnt[b];
    int cnt = (int)(bc < BCAP ? bc : BCAP);
    for (int k = threadIdx.x; k < cnt; k += 256)
        atomicAdd(&lc[bpair[(size_t)b * BCAP + k] >> 16], 1u);
    unsigned oc_u = *ovf_cnt;
    int oc = (int)(oc_u < OVCAP ? oc_u : OVCAP);
    for (int k = threadIdx.x; k < oc; k += 256) {
        uint2 pp = ovf[k];
        if ((int)(pp.y >> 7) == b) atomicAdd(&lc[pp.y & 127u], 1u);
    }
    __syncthreads();
    int i = base + threadIdx.x;
    if (threadIdx.x < 128 && i < n) counts[i] = lc[threadIdx.x];
}

__global__ __launch_bounds__(256) void scan_reduce_kernel(const unsigned* __restrict__ counts,
                                                          unsigned* __restrict__ partials, int n)
{
    __shared__ unsigned sm[256];
    int t = threadIdx.x;
    int i = blockIdx.x * 256 + t;
    unsigned v = (i < n) ? counts[i] : 0u;
    sm[t] = v;
    __syncthreads();
#pragma unroll
    for (int off = 128; off > 0; off >>= 1) {
        if (t < off) sm[t] += sm[t + off];
        __syncthreads();
    }
    if (t == 0) partials[blockIdx.x] = sm[0];
}

__global__ __launch_bounds__(256) void scan_partials_kernel(unsigned* __restrict__ partials,
                                                            unsigned* __restrict__ rs, int nb, int n)
{
    __shared__ unsigned sm[256];
    int t = threadIdx.x;
    unsigned v = (t < nb) ? partials[t] : 0u;
    sm[t] = v;
    __syncthreads();
#pragma unroll
    for (int off = 1; off < 256; off <<= 1) {
        unsigned u = (t >= off) ? sm[t - off] : 0u;
        __syncthreads();
        sm[t] += u;
        __syncthreads();
    }
    if (t < nb) partials[t] = sm[t] - v;
    if (t == 255) rs[n] = sm[255];
}

__global__ __launch_bounds__(256) void scan_write_kernel(const unsigned* __restrict__ counts,
                                                         const unsigned* __restrict__ partials,
                                                         unsigned* __restrict__ rs,
                                                         float* __restrict__ nrm, int n)
{
    __shared__ unsigned sm[256];
    int t = threadIdx.x;
    int i = blockIdx.x * 256 + t;
    unsigned c = (i < n) ? counts[i] : 0u;
    sm[t] = c;
    __syncthreads();
#pragma unroll
    for (int off = 1; off < 256; off <<= 1) {
        unsigned u = (t >= off) ? sm[t - off] : 0u;
        __syncthreads();
        sm[t] += u;
        __syncthreads();
    }
    if (i < n) {
        rs[i] = partials[blockIdx.x] + sm[t] - c;
        nrm[i] = rsqrtf((float)(c + 1u));
    }
}

__global__ __launch_bounds__(256) void bucket_place_kernel(
    const unsigned* __restrict__ bcnt, const unsigned* __restrict__ bpair,
    const unsigned* __restrict__ rs, unsigned* __restrict__ csr_src,
    unsigned* __restrict__ cursor, int n)
{
    __shared__ unsigned lc[128];
    __shared__ unsigned rbase[128];
    const int b = blockIdx.x, base = b << 7;
    if (threadIdx.x < 128) {
        lc[threadIdx.x] = 0;
        int i = base + threadIdx.x;
        rbase[threadIdx.x] = (i < n) ? rs[i] : 0u;
    }
    __syncthreads();
    unsigned bc = bcnt[b];
    int cnt = (int)(bc < BCAP ? bc : BCAP);
    for (int k = threadIdx.x; k < cnt; k += 256) {
        unsigned v = bpair[(size_t)b * BCAP + k];
        unsigned ld = v >> 16;
        unsigned r = atomicAdd(&lc[ld], 1u);
        csr_src[rbase[ld] + r] = v & 0xFFFFu;
    }
    __syncthreads();
    int i = base + threadIdx.x;
    if (threadIdx.x < 128 && i < n) cursor[i] = rbase[threadIdx.x] + lc[threadIdx.x];
}

__global__ void overflow_fill_kernel(const unsigned* __restrict__ ovf_cnt,
                                     const uint2* __restrict__ ovf,
                                     unsigned* __restrict__ cursor,
                                     unsigned* __restrict__ csr_src)
{
    unsigned oc_u = *ovf_cnt;
    int oc = (int)(oc_u < OVCAP ? oc_u : OVCAP);
    for (int k = threadIdx.x; k < oc; k += 256) {
        uint2 pp = ovf[k];
        unsigned pos = atomicAdd(&cursor[pp.y], 1u);
        csr_src[pos] = pp.x;
    }
}

// -------- fused layer-1 aggregation: single-pass, LDS-free, 3-deep pipe -----
// One wave per node. Lane L: edge-slot e=L>>4 (4 edges per step), chunk
// c=L&15 (uint4 = 8 of 128 GAT channels); chunks c<4 also carry the GCN row
// (uint4 = 8 of 32 channels at row offset +16). csr indices preloaded with
// one coalesced load and distributed via __shfl. 3-deep rolling software
// pipeline: 12 edges in flight per wave (up from 8) for more MLP while
// staying under the 64-VGPR occupancy cliff.
__global__ __launch_bounds__(256) void agg1_fused_kernel(
    const unsigned* __restrict__ hb,
    const float* __restrict__ as1, const float* __restrict__ ad1,
    const float* __restrict__ nrm,
    const unsigned* __restrict__ rs, const unsigned* __restrict__ csr_src,
    const float* __restrict__ gat_b1, const float* __restrict__ gcn_b1,
    unsigned* __restrict__ xgb, unsigned* __restrict__ gaccb, int n)
{
    const int wid = threadIdx.x >> 6;
    const int lane = threadIdx.x & 63;
    const int i = blockIdx.x * 4 + wid;
    if (i >= n) return;
    const unsigned beg = rs[i];
    const int deg = (int)(rs[i + 1] - beg);
    const float4* as1v = (const float4*)as1;
    const uint4*  hv4  = (const uint4*)hb;     // row = 20 uint4 (16 GAT + 4 GCN)

    const int e = lane >> 4, c = lane & 15;
    const int h = c >> 2;
    const bool gc = c < 4;

    const float4 dv = ((const float4*)ad1)[i];
    const float dvh = sel4(dv, h);
    const float ni  = nrm[i];

    // coalesced csr preload (covers deg<=64; rare tail handled below)
    unsigned pre = (lane < deg) ? csr_src[beg + lane] : (unsigned)i;

    const float4 av = as1v[i];
    const float eself = __expf(leakyf(sel4(av, h) + dvh));

    float acc[8], gacc[8];
#pragma unroll
    for (int t = 0; t < 8; ++t) { acc[t] = 0.f; gacc[t] = 0.f; }
    float sumw = 0.f;

    // self contribution (once, on e==0 slot)
    if (e == 0) {
        uint4 hv = hv4[(size_t)i * 20 + c];
        float2 p0 = unpack2_bf16(hv.x), p1 = unpack2_bf16(hv.y);
        float2 p2 = unpack2_bf16(hv.z), p3 = unpack2_bf16(hv.w);
        acc[0] = p0.x * eself; acc[1] = p0.y * eself;
        acc[2] = p1.x * eself; acc[3] = p1.y * eself;
        acc[4] = p2.x * eself; acc[5] = p2.y * eself;
        acc[6] = p3.x * eself; acc[7] = p3.y * eself;
        if (gc) {
            uint4 gv = hv4[(size_t)i * 20 + 16 + c];
            float w2s = ni * ni;
            float2 q0 = unpack2_bf16(gv.x), q1 = unpack2_bf16(gv.y);
            float2 q2 = unpack2_bf16(gv.z), q3 = unpack2_bf16(gv.w);
            gacc[0] = q0.x * w2s; gacc[1] = q0.y * w2s;
            gacc[2] = q1.x * w2s; gacc[3] = q1.y * w2s;
            gacc[4] = q2.x * w2s; gacc[5] = q2.y * w2s;
            gacc[6] = q3.x * w2s; gacc[7] = q3.y * w2s;
        }
    }

    const int dfast = deg < 64 ? deg : 64;
    const int steps = (dfast + 3) >> 2;

    auto fetch = [&](int idx, float4& a, uint4& hh, uint4& gg, float& nr) {
        unsigned s = __shfl(pre, idx, 64);
        if (idx >= deg) s = (unsigned)i;
        a = as1v[s];
        hh = hv4[(size_t)s * 20 + c];
        if (gc) { gg = hv4[(size_t)s * 20 + 16 + c]; nr = nrm[s]; }
    };

    float4 a0 = make_float4(0.f, 0.f, 0.f, 0.f), a1 = a0, a2 = a0;
    uint4  h0 = make_uint4(0u, 0u, 0u, 0u), h1 = h0, h2 = h0;
    uint4  g0 = h0, g1 = h0, g2 = h0;
    float  n0 = 0.f, n1 = 0.f, n2 = 0.f;
    if (steps > 0) fetch(e, a0, h0, g0, n0);
    if (steps > 1) fetch(4 + e, a1, h1, g1, n1);
    for (int j = 0; j < steps; ++j) {
        if (j + 2 < steps) fetch((j + 2) * 4 + e, a2, h2, g2, n2);
        const bool val = (j * 4 + e) < deg;
        float w = __expf(leakyf(sel4(a0, h) + dvh));
        w = val ? w : 0.f;
        sumw += w;
        {
            float2 p0 = unpack2_bf16(h0.x), p1 = unpack2_bf16(h0.y);
            float2 p2 = unpack2_bf16(h0.z), p3 = unpack2_bf16(h0.w);
            acc[0] = fmaf(p0.x, w, acc[0]); acc[1] = fmaf(p0.y, w, acc[1]);
            acc[2] = fmaf(p1.x, w, acc[2]); acc[3] = fmaf(p1.y, w, acc[3]);
            acc[4] = fmaf(p2.x, w, acc[4]); acc[5] = fmaf(p2.y, w, acc[5]);
            acc[6] = fmaf(p3.x, w, acc[6]); acc[7] = fmaf(p3.y, w, acc[7]);
        }
        if (gc) {
            float cw = val ? n0 * ni : 0.f;
            float2 q0 = unpack2_bf16(g0.x), q1 = unpack2_bf16(g0.y);
            float2 q2 = unpack2_bf16(g0.z), q3 = unpack2_bf16(g0.w);
            gacc[0] = fmaf(q0.x, cw, gacc[0]); gacc[1] = fmaf(q0.y, cw, gacc[1]);
            gacc[2] = fmaf(q1.x, cw, gacc[2]); gacc[3] = fmaf(q1.y, cw, gacc[3]);
            gacc[4] = fmaf(q2.x, cw, gacc[4]); gacc[5] = fmaf(q2.y, cw, gacc[5]);
            gacc[6] = fmaf(q3.x, cw, gacc[6]); gacc[7] = fmaf(q3.y, cw, gacc[7]);
        }
        a0 = a1; h0 = h1; g0 = g1; n0 = n1;
        a1 = a2; h1 = h2; g1 = g2; n1 = n2;
    }
    // rare tail: deg > 64
    for (int j4 = 64; j4 < deg; j4 += 4) {
        int idx = j4 + e;
        bool val = idx < deg;
        unsigned s = val ? csr_src[beg + idx] : (unsigned)i;
        float4 a = as1v[s];
        float w = val ? __expf(leakyf(sel4(a, h) + dvh)) : 0.f;
        sumw += w;
        uint4 hv = hv4[(size_t)s * 20 + c];
        float2 p0 = unpack2_bf16(hv.x), p1 = unpack2_bf16(hv.y);
        float2 p2 = unpack2_bf16(hv.z), p3 = unpack2_bf16(hv.w);
        acc[0] = fmaf(p0.x, w, acc[0]); acc[1] = fmaf(p0.y, w, acc[1]);
        acc[2] = fmaf(p1.x, w, acc[2]); acc[3] = fmaf(p1.y, w, acc[3]);
        acc[4] = fmaf(p2.x, w, acc[4]); acc[5] = fmaf(p2.y, w, acc[5]);
        acc[6] = fmaf(p3.x, w, acc[6]); acc[7] = fmaf(p3.y, w, acc[7]);
        if (gc) {
            float cw = val ? nrm[s] * ni : 0.f;
            uint4 gv = hv4[(size_t)s * 20 + 16 + c];
            float2 q0 = unpack2_bf16(gv.x), q1 = unpack2_bf16(gv.y);
            float2 q2 = unpack2_bf16(gv.z), q3 = unpack2_bf16(gv.w);
            gacc[0] = fmaf(q0.x, cw, gacc[0]); gacc[1] = fmaf(q0.y, cw, gacc[1]);
            gacc[2] = fmaf(q1.x, cw, gacc[2]); gacc[3] = fmaf(q1.y, cw, gacc[3]);
            gacc[4] = fmaf(q2.x, cw, gacc[4]); gacc[5] = fmaf(q2.y, cw, gacc[5]);
            gacc[6] = fmaf(q3.x, cw, gacc[6]); gacc[7] = fmaf(q3.y, cw, gacc[7]);
        }
    }

    // fold edge-slot replicas (xor 16/32 keeps c, mixes e)
#pragma unroll
    for (int t = 0; t < 8; ++t) {
        acc[t]  += __shfl_xor(acc[t], 16, 64);
        acc[t]  += __shfl_xor(acc[t], 32, 64);
        gacc[t] += __shfl_xor(gacc[t], 16, 64);
        gacc[t] += __shfl_xor(gacc[t], 32, 64);
    }
    sumw += __shfl_xor(sumw, 16, 64);
    sumw += __shfl_xor(sumw, 32, 64);
    const float ssh = sumw + eself;

    if (e == 0) {                             // lanes 0-15: final 8ch each
        float inv = 1.f / ssh;
        float4 b0 = *(const float4*)&gat_b1[c * 8];
        float4 b1 = *(const float4*)&gat_b1[c * 8 + 4];
        float o[8] = {acc[0] * inv + b0.x, acc[1] * inv + b0.y,
                      acc[2] * inv + b0.z, acc[3] * inv + b0.w,
                      acc[4] * inv + b1.x, acc[5] * inv + b1.y,
                      acc[6] * inv + b1.z, acc[7] * inv + b1.w};
#pragma unroll
        for (int t = 0; t < 8; ++t) o[t] = o[t] > 0.f ? o[t] : __expf(o[t]) - 1.f;
        uint4 pv = make_uint4(pack2_bf16(o[0], o[1]), pack2_bf16(o[2], o[3]),
                              pack2_bf16(o[4], o[5]), pack2_bf16(o[6], o[7]));
        ((uint4*)xgb)[(size_t)i * 16 + c] = pv;
        if (gc) {                             // lanes 0-3: final gcn 8ch each
            float4 c0 = *(const float4*)&gcn_b1[c * 8];
            float4 c1 = *(const float4*)&gcn_b1[c * 8 + 4];
            float g[8] = {fmaxf(gacc[0] + c0.x, 0.f), fmaxf(gacc[1] + c0.y, 0.f),
                          fmaxf(gacc[2] + c0.z, 0.f), fmaxf(gacc[3] + c0.w, 0.f),
                          fmaxf(gacc[4] + c1.x, 0.f), fmaxf(gacc[5] + c1.y, 0.f),
                          fmaxf(gacc[6] + c1.z, 0.f), fmaxf(gacc[7] + c1.w, 0.f)};
            uint4 gv = make_uint4(pack2_bf16(g[0], g[1]), pack2_bf16(g[2], g[3]),
                                  pack2_bf16(g[4], g[5]), pack2_bf16(g[6], g[7]));
            ((uint4*)gaccb)[(size_t)i * 4 + c] = gv;
        }
    }
}

// ---------------- fused layer-2 aggregation: single-pass, 4-deep pipe -------
// Lane L: edge-slot e=L&3, chunk c=L>>2 (10 chunks: c<5 GAT / c>=5 GCN).
// GAT lanes load as2[s] and compute w inline; GCN lanes load nrm[s].
// 4-deep rolling pipeline (16 edges in flight). Fold over e with xor 1,2.
__global__ __launch_bounds__(256) void agg2_fused_kernel(
    const unsigned* __restrict__ hg_b, const float* __restrict__ as2,
    const float* __restrict__ ad2, const float* __restrict__ nrm,
    const unsigned* __restrict__ rs, const unsigned* __restrict__ csr_src,
    const float* __restrict__ gat_b2, const float* __restrict__ gcn_b2,
    const float* __restrict__ wc_p, const float* __restrict__ wt_p,
    float* __restrict__ cat, int n)
{
    const int wid = threadIdx.x >> 6;
    const int lane = threadIdx.x & 63;
    const int i = blockIdx.x * 4 + wid;
    if (i >= n) return;
    const unsigned beg = rs[i];
    const int deg = (int)(rs[i + 1] - beg);
    const int e = lane & 3, c = lane >> 2;
    const bool act = c < 10, isgat = c < 5;
    const float adv = ad2[i];
    const float ni = nrm[i];
    const uint4* hgv = (const uint4*)hg_b;    // row = 10 uint4

    unsigned pre = (lane < deg) ? csr_src[beg + lane] : (unsigned)i;
    const float eself = __expf(leakyf(as2[i] + adv));

    float acc[8];
#pragma unroll
    for (int t = 0; t < 8; ++t) acc[t] = 0.f;
    float sumw = 0.f;

    if (act && e == 0) {                      // self contribution once
        uint4 hv = hgv[(size_t)i * 10 + c];
        float sw = isgat ? eself : ni * ni;
        float2 p0 = unpack2_bf16(hv.x), p1 = unpack2_bf16(hv.y);
        float2 p2 = unpack2_bf16(hv.z), p3 = unpack2_bf16(hv.w);
        acc[0] = p0.x * sw; acc[1] = p0.y * sw;
        acc[2] = p1.x * sw; acc[3] = p1.y * sw;
        acc[4] = p2.x * sw; acc[5] = p2.y * sw;
        acc[6] = p3.x * sw; acc[7] = p3.y * sw;
    }

    const int dfast = deg < 64 ? deg : 64;
    const int steps = (dfast + 3) >> 2;

    auto fetch = [&](int idx, float& aw, uint4& hh) {
        unsigned s = __shfl(pre, idx, 64);
        if (idx >= deg) s = (unsigned)i;
        if (act) { aw = isgat ? as2[s] : nrm[s]; hh = hgv[(size_t)s * 10 + c]; }
    };

    float aw0 = 0.f, aw1 = 0.f, aw2 = 0.f, aw3 = 0.f;
    uint4 q0 = make_uint4(0u, 0u, 0u, 0u), q1 = q0, q2 = q0, q3 = q0;
    if (steps > 0) fetch(e, aw0, q0);
    if (steps > 1) fetch(4 + e, aw1, q1);
    if (steps > 2) fetch(8 + e, aw2, q2);
    for (int j = 0; j < steps; ++j) {
        if (j + 3 < steps) fetch((j + 3) * 4 + e, aw3, q3);
        const bool val = (j * 4 + e) < deg;
        float w;
        if (isgat) {
            w = __expf(leakyf(aw0 + adv));
            w = val ? w : 0.f;
            sumw += w;
        } else {
            w = val ? aw0 * ni : 0.f;
        }
        if (act) {
            float2 p0 = unpack2_bf16(q0.x), p1 = unpack2_bf16(q0.y);
            float2 p2 = unpack2_bf16(q0.z), p3 = unpack2_bf16(q0.w);
            acc[0] = fmaf(p0.x, w, acc[0]); acc[1] = fmaf(p0.y, w, acc[1]);
            acc[2] = fmaf(p1.x, w, acc[2]); acc[3] = fmaf(p1.y, w, acc[3]);
            acc[4] = fmaf(p2.x, w, acc[4]); acc[5] = fmaf(p2.y, w, acc[5]);
            acc[6] = fmaf(p3.x, w, acc[6]); acc[7] = fmaf(p3.y, w, acc[7]);
        }
        aw0 = aw1; q0 = q1;
        aw1 = aw2; q1 = q2;
        aw2 = aw3; q2 = q3;
    }
    for (int j4 = 64; j4 < deg; j4 += 4) {    // rare tail
        int idx = j4 + e;
        bool val = idx < deg;
        unsigned s = val ? csr_src[beg + idx] : (unsigned)i;
        if (act) {
            float aw = isgat ? as2[s] : nrm[s];
            float w;
            if (isgat) {
                w = val ? __expf(leakyf(aw + adv)) : 0.f;
                sumw += w;
            } else {
                w = val ? aw * ni : 0.f;
            }
            uint4 hv = hgv[(size_t)s * 10 + c];
            float2 p0 = unpack2_bf16(hv.x), p1 = unpack2_bf16(hv.y);
            float2 p2 = unpack2_bf16(hv.z), p3 = unpack2_bf16(hv.w);
            acc[0] = fmaf(p0.x, w, acc[0]); acc[1] = fmaf(p0.y, w, acc[1]);
            acc[2] = fmaf(p1.x, w, acc[2]); acc[3] = fmaf(p1.y, w, acc[3]);
            acc[4] = fmaf(p2.x, w, acc[4]); acc[5] = fmaf(p2.y, w, acc[5]);
            acc[6] = fmaf(p3.x, w, acc[6]); acc[7] = fmaf(p3.y, w, acc[7]);
        }
    }

#pragma unroll
    for (int t = 0; t < 8; ++t) {
        acc[t] += __shfl_xor(acc[t], 1, 64);
        acc[t] += __shfl_xor(acc[t], 2, 64);
    }
    sumw += __shfl_xor(sumw, 1, 64);
    sumw += __shfl_xor(sumw, 2, 64);
    const float ssum = sumw + eself;

    if (act && e == 0) {
        if (isgat) {
            float inv = 1.f / ssum, wt = *wt_p;
            float4 b0 = *(const float4*)&gat_b2[c * 8];
            float4 b1 = *(const float4*)&gat_b2[c * 8 + 4];
            float4 o0 = make_float4((acc[0] * inv + b0.x) * wt, (acc[1] * inv + b0.y) * wt,
                                    (acc[2] * inv + b0.z) * wt, (acc[3] * inv + b0.w) * wt);
            float4 o1 = make_float4((acc[4] * inv + b1.x) * wt, (acc[5] * inv + b1.y) * wt,
                                    (acc[6] * inv + b1.z) * wt, (acc[7] * inv + b1.w) * wt);
            *(float4*)&cat[(size_t)i * 80 + 40 + c * 8]     = o0;
            *(float4*)&cat[(size_t)i * 80 + 40 + c * 8 + 4] = o1;
        } else {
            float wc = *wc_p;
            int g = c - 5;
            float4 b0 = *(const float4*)&gcn_b2[g * 8];
            float4 b1 = *(const float4*)&gcn_b2[g * 8 + 4];
            float4 o0 = make_float4((acc[0] + b0.x) * wc, (acc[1] + b0.y) * wc,
                                    (acc[2] + b0.z) * wc, (acc[3] + b0.w) * wc);
            float4 o1 = make_float4((acc[4] + b1.x) * wc, (acc[5] + b1.y) * wc,
                                    (acc[6] + b1.z) * wc, (acc[7] + b1.w) * wc);
            *(float4*)&cat[(size_t)i * 80 + g * 8]     = o0;
            *(float4*)&cat[(size_t)i * 80 + g * 8 + 4] = o1;
        }
    }
}

// ---------------- host ------------------------------------------------------
extern "C" void kernel_launch(void* const* d_in, const int* in_sizes, int n_in,
                              void* d_out, int out_size, void* d_ws, size_t ws_size,
                              hipStream_t stream)
{
    const float* x        = (const float*)d_in[0];
    const int*   eidx     = (const int*)d_in[1];
    const float* gat_W1   = (const float*)d_in[2];
    const float* att_s1   = (const float*)d_in[3];
    const float* att_d1   = (const float*)d_in[4];
    const float* gat_b1   = (const float*)d_in[5];
    const float* gat_W2   = (const float*)d_in[6];
    const float* att_s2   = (const float*)d_in[7];
    const float* att_d2   = (const float*)d_in[8];
    const float* gat_b2   = (const float*)d_in[9];
    const float* gcn_W1   = (const float*)d_in[10];
    const float* gcn_b1   = (const float*)d_in[11];
    const float* gcn_W2   = (const float*)d_in[12];
    const float* gcn_b2   = (const float*)d_in[13];
    const float* lin_W    = (const float*)d_in[14];
    const float* lin_b    = (const float*)d_in[15];
    const float* wc_p     = (const float*)d_in[16];
    const float* wt_p     = (const float*)d_in[17];

    const int n = in_sizes[0] / F_IN;      // 50000
    const int e = in_sizes[1] / 2;         // 800000
    const int* src = eidx;
    const int* dst = eidx + e;
    const int NBUCK = (n + 127) >> 7;      // 391

    char* p = (char*)d_ws;
    auto alloc = [&](size_t bytes) -> void* {
        void* r = (void*)p;
        p += (bytes + 255) & ~(size_t)255;
        return r;
    };
    unsigned* counts  = (unsigned*)alloc((size_t)n * 4);
    unsigned* rs      = (unsigned*)alloc((size_t)(n + 1) * 4);
    unsigned* cursor  = (unsigned*)alloc((size_t)n * 4);
    unsigned* partials= (unsigned*)alloc(256 * 4);
    unsigned* bcnt    = (unsigned*)alloc((size_t)(NBUCK + 1) * 4);
    unsigned* csr_src = (unsigned*)alloc((size_t)e * 4);
    uint4*    wbf     = (uint4*)alloc(40 * 64 * 16);
    float* nrm     = (float*)alloc((size_t)n * 4);
    float* as1     = (float*)alloc((size_t)n * 4 * 4);
    float* ad1     = (float*)alloc((size_t)n * 4 * 4);
    float* as2     = (float*)alloc((size_t)n * 4);
    float* ad2     = (float*)alloc((size_t)n * 4);
    float* cat     = (float*)alloc((size_t)n * 80 * 4);   // agg2 out; earlier: bpair, hb
    unsigned* hg_b = (unsigned*)alloc((size_t)n * 40 * 4);
    float* xg      = (float*)alloc((size_t)n * F_IN * 4); // xgb bf16
    unsigned* gaccb= (unsigned*)alloc((size_t)n * 16 * 4);
    // aliases with disjoint lifetimes (stream-ordered):
    unsigned* bpair = (unsigned*)cat;
    uint2*    ovf   = (uint2*)(bpair + (size_t)NBUCK * BCAP);
    unsigned* hb    = (unsigned*)cat;                     // [n][80] combined h1 after CSR build
    unsigned* xgb   = (unsigned*)xg;
    unsigned* ovf_cnt = bcnt + NBUCK;

    const int NB = (n + 255) / 256;
    const int WB = (n + 3) / 4;
    const int SB = (e + SCHUNK - 1) / SCHUNK;

    // ---- CSR build ----
    hipMemsetAsync(bcnt, 0, (size_t)(NBUCK + 1) * 4, stream);
    bucket_scatter_kernel<<<SB, 256, 0, stream>>>(src, dst, bcnt, bpair, ovf_cnt, ovf, e, NBUCK);
    bucket_count_kernel<<<NBUCK, 256, 0, stream>>>(bcnt, bpair, ovf_cnt, ovf, counts, n);
    scan_reduce_kernel<<<NB, 256, 0, stream>>>(counts, partials, n);
    scan_partials_kernel<<<1, 256, 0, stream>>>(partials, rs, NB, n);
    scan_write_kernel<<<NB, 256, 0, stream>>>(counts, partials, rs, nrm, n);
    bucket_place_kernel<<<NBUCK, 256, 0, stream>>>(bcnt, bpair, rs, csr_src, cursor, n);
    overflow_fill_kernel<<<1, 256, 0, stream>>>(ovf_cnt, ovf, cursor, csr_src);

    // ---- W pre-pack + MFMA first-layer GEMM (fused logits1) ----
    wb_prep_kernel<<<40, 64, 0, stream>>>(gat_W1, gcn_W1, wbf);
    gemm1_mfma_kernel<<<(n + 63) / 64, 256, 0, stream>>>(x, wbf, att_s1, att_d1,
                                                         hb, as1, ad1, n);

    // ---- fused layer-1 aggregation (single-pass GAT softmax + GCN norm) ----
    agg1_fused_kernel<<<WB, 256, 0, stream>>>(hb, as1, ad1, nrm, rs, csr_src,
                                              gat_b1, gcn_b1, xgb, gaccb, n);

    // ---- layer-2 GEMMs into hg_b (gat gemm fuses logits2) ----
    gemm_tile_bb<32, 40, 128, 32, 40, 20><<<(n + 127) / 128, 320, 0, stream>>>(gaccb, gcn_W2, hg_b, n);
    gemm2_gat_kernel<<<(n + 127) / 128, 320, 0, stream>>>(xgb, gat_W2, att_s2, att_d2,
                                                          hg_b, as2, ad2, n);

    // ---- fused layer-2 aggregation -> cat ----
    agg2_fused_kernel<<<WB, 256, 0, stream>>>(hg_b, as2, ad2, nrm, rs, csr_src,
                                              gat_b2, gcn_b2, wc_p, wt_p, cat, n);

    // ---- head ----
    gemm_tile<80, 40, 128, 40><<<(n + 127) / 128, 320, 0, stream>>>(cat, lin_W, lin_b, (float*)d_out, n);
}